// Round 3
// baseline (5257.250 us; speedup 1.0000x reference)
//
#include <hip/hip_runtime.h>
#include <math.h>

// ---------------------------------------------------------------------------
// KimiDeltaAttention forward, MI355X. Round 3: fix non-bijective LDS swizzle
// (chunks 7/8 collided -> corrupted every GEMM + the scan). fp32 compute,
// bf16 scan streams. Shapes fixed: B=2, T=4096, D=2048, H=16, Dk=Dv=128.
// ---------------------------------------------------------------------------

constexpr int NB = 2, NT = 4096, ND = 2048, NH = 16, DK = 128, DV = 128;
constexpr int MROWS = NB * NT;   // 8192
constexpr int BHN   = NB * NH;   // 32

#define DEV static __device__ __forceinline__

DEV float sigmoidf_(float x) { return 1.0f / (1.0f + expf(-x)); }

DEV float bf2f(unsigned u) { return __uint_as_float(u << 16); }
DEV unsigned f2bf(float f) {  // round-to-nearest-even
    unsigned u = __float_as_uint(f);
    return (u + 0x7fffu + ((u >> 16) & 1u)) >> 16;
}
DEV unsigned pack2(float a, float b) { return f2bf(a) | (f2bf(b) << 16); }

// Bijective XOR swizzle on float4-group index p in [0,32): p' = p ^ (p>>3).
// (p = 8a+b -> 8a + (b^a); bijection per 8-group. 16 lanes reading groups
// 2*lane (or 2*lane+1) hit each bank-quad exactly twice -> 2-way = free.)
DEV int swz4(int p) { return p ^ (p >> 3); }

DEV float4 bflo(uint4 U) {
    return make_float4(bf2f(U.x & 0xffff), bf2f(U.x >> 16),
                       bf2f(U.y & 0xffff), bf2f(U.y >> 16));
}
DEV float4 bfhi(uint4 U) {
    return make_float4(bf2f(U.z & 0xffff), bf2f(U.z >> 16),
                       bf2f(U.w & 0xffff), bf2f(U.w >> 16));
}

// 16-lane butterfly sum via DPP (VALU pipe; groups = 16 consecutive lanes)
template <int CTRL>
DEV float dppadd(float x) {
    int y = __builtin_amdgcn_mov_dpp(__float_as_int(x), CTRL, 0xF, 0xF, true);
    return x + __int_as_float(y);
}
DEV float reduce16f(float x) {
    x = dppadd<0xB1>(x);   // quad_perm xor1
    x = dppadd<0x4E>(x);   // quad_perm xor2
    x = dppadd<0x141>(x);  // row_half_mirror
    x = dppadd<0x140>(x);  // row_mirror
    return x;              // all 16 lanes hold the sum
}

// ---------------------------------------------------------------------------
// fp32 tiled GEMM: C[M,N] = A[M,K] @ B[K,N].  BM=BN=128, BK=16, 256 threads,
// 8x8 micro-tile per thread. Bs float4-groups XOR-swizzled (bijective).
// Requires M%128==0, N%128==0, K%16==0.
// ---------------------------------------------------------------------------
__global__ __launch_bounds__(256) void gemm_f32(
    const float* __restrict__ A, const float* __restrict__ Bm,
    float* __restrict__ C, int Md, int Nd, int Kd)
{
    constexpr int BMt = 128, BNt = 128, BKt = 16;
    __shared__ float As[BKt][BMt + 4];  // [16][132], k-major
    __shared__ float Bs[BKt][128];      // [16][128], XOR-swizzled groups

    const int nbx = Nd / BNt;
    const int bx = blockIdx.x % nbx;
    const int by = blockIdx.x / nbx;
    const int m0 = by * BMt, n0 = bx * BNt;
    const int tid = threadIdx.x;
    const int tx = tid & 15, ty = tid >> 4;
    const int arow = tid >> 1, ak = (tid & 1) * 8;
    const int brow = tid >> 4, bc8 = tid & 15;
    const int glo = swz4(2 * bc8) * 4;      // bc8 == tx, so same for read side
    const int ghi = swz4(2 * bc8 + 1) * 4;

    float acc[8][8];
#pragma unroll
    for (int i = 0; i < 8; i++)
#pragma unroll
        for (int j = 0; j < 8; j++) acc[i][j] = 0.f;

    for (int k0 = 0; k0 < Kd; k0 += BKt) {
        const float* ap = A + (size_t)(m0 + arow) * Kd + k0 + ak;
        float4 a0 = *(const float4*)ap;
        float4 a1 = *(const float4*)(ap + 4);
        const float* bp = Bm + (size_t)(k0 + brow) * Nd + n0 + bc8 * 8;
        float4 b0 = *(const float4*)bp;
        float4 b1 = *(const float4*)(bp + 4);
        __syncthreads();
        As[ak + 0][arow] = a0.x; As[ak + 1][arow] = a0.y;
        As[ak + 2][arow] = a0.z; As[ak + 3][arow] = a0.w;
        As[ak + 4][arow] = a1.x; As[ak + 5][arow] = a1.y;
        As[ak + 6][arow] = a1.z; As[ak + 7][arow] = a1.w;
        *(float4*)(&Bs[brow][0] + glo) = b0;
        *(float4*)(&Bs[brow][0] + ghi) = b1;
        __syncthreads();
#pragma unroll
        for (int kk = 0; kk < BKt; kk++) {
            float4 av0 = *(const float4*)&As[kk][ty * 8];
            float4 av1 = *(const float4*)&As[kk][ty * 8 + 4];
            float4 bv0 = *(const float4*)(&Bs[kk][0] + glo);
            float4 bv1 = *(const float4*)(&Bs[kk][0] + ghi);
            float a[8] = {av0.x, av0.y, av0.z, av0.w, av1.x, av1.y, av1.z, av1.w};
            float b[8] = {bv0.x, bv0.y, bv0.z, bv0.w, bv1.x, bv1.y, bv1.z, bv1.w};
#pragma unroll
            for (int i = 0; i < 8; i++)
#pragma unroll
                for (int j = 0; j < 8; j++) acc[i][j] += a[i] * b[j];
        }
    }
#pragma unroll
    for (int i = 0; i < 8; i++) {
        float4 o0, o1;
        o0.x = acc[i][0]; o0.y = acc[i][1]; o0.z = acc[i][2]; o0.w = acc[i][3];
        o1.x = acc[i][4]; o1.y = acc[i][5]; o1.z = acc[i][6]; o1.w = acc[i][7];
        float* cp = C + (size_t)(m0 + ty * 8 + i) * Nd + n0 + tx * 8;
        *(float4*)cp       = o0;
        *(float4*)(cp + 4) = o1;
    }
}

// ---------------------------------------------------------------------------
// Causal depthwise conv (K=4) + silu, optional l2norm (+q scale).
// in: pre [B*T, 2048] fp32; w [2048,4]; out transposed [B*H, T, 128] BF16.
// MODE: 0 = silu only (v), 1 = +l2norm (k), 2 = +l2norm*Dk^-0.5 (q).
// ---------------------------------------------------------------------------
template <int MODE>
__global__ __launch_bounds__(256) void conv_silu(
    const float* __restrict__ pre, const float* __restrict__ cw,
    unsigned short* __restrict__ outp)
{
    const int m = blockIdx.x;
    const int t = m & (NT - 1);
    const int b = m >> 12;
    const int tid = threadIdx.x;
    const int hd = tid * 8;
    const int h  = hd >> 7;
    const int d0 = hd & 127;

    float xr[4][8];
#pragma unroll
    for (int i = 0; i < 4; i++) {
        const int tt = t - 3 + i;
        if (tt >= 0) {
            const float* p = pre + (size_t)(m - 3 + i) * ND + hd;
            float4 u0 = *(const float4*)p;
            float4 u1 = *(const float4*)(p + 4);
            xr[i][0] = u0.x; xr[i][1] = u0.y; xr[i][2] = u0.z; xr[i][3] = u0.w;
            xr[i][4] = u1.x; xr[i][5] = u1.y; xr[i][6] = u1.z; xr[i][7] = u1.w;
        } else {
#pragma unroll
            for (int j = 0; j < 8; j++) xr[i][j] = 0.f;
        }
    }
    float y[8];
    float ssum = 0.f;
#pragma unroll
    for (int j = 0; j < 8; j++) {
        float4 w = *(const float4*)&cw[(size_t)(hd + j) * 4];
        float v = xr[0][j] * w.x + xr[1][j] * w.y + xr[2][j] * w.z + xr[3][j] * w.w;
        v = v * sigmoidf_(v);  // silu
        y[j] = v;
        ssum += v * v;
    }
    float scale = 1.f;
    if (MODE >= 1) {
        ssum = reduce16f(ssum);
        scale = rsqrtf(ssum + 1e-6f);
        if (MODE == 2) scale *= 0.08838834764831845f;  // Dk^-0.5
    }
    uint4 pk;
    pk.x = pack2(y[0] * scale, y[1] * scale);
    pk.y = pack2(y[2] * scale, y[3] * scale);
    pk.z = pack2(y[4] * scale, y[5] * scale);
    pk.w = pack2(y[6] * scale, y[7] * scale);
    unsigned short* dst = outp + ((size_t)(b * NH + h) * NT + t) * 128 + d0;
    *(uint4*)dst = pk;
}

// ---------------------------------------------------------------------------
// decay[b,h,t,d] = exp(-exp(A_log[h]) * softplus(g + dt_bias)), bf16, transposed
// ---------------------------------------------------------------------------
__global__ __launch_bounds__(256) void decay_k(
    const float* __restrict__ g, const float* __restrict__ A_log,
    const float* __restrict__ dtb, unsigned short* __restrict__ dec)
{
    const int m = blockIdx.x;
    const int t = m & (NT - 1);
    const int b = m >> 12;
    const int tid = threadIdx.x;
    const int hd = tid * 8, h = hd >> 7, d0 = hd & 127;
    const float ea = expf(A_log[h]);
    const float* gp = g + (size_t)m * ND + hd;
    float4 g0 = *(const float4*)gp, g1 = *(const float4*)(gp + 4);
    float4 b0 = *(const float4*)&dtb[hd], b1 = *(const float4*)&dtb[hd + 4];
    float xin[8] = {g0.x + b0.x, g0.y + b0.y, g0.z + b0.z, g0.w + b0.w,
                    g1.x + b1.x, g1.y + b1.y, g1.z + b1.z, g1.w + b1.w};
    float r[8];
#pragma unroll
    for (int j = 0; j < 8; j++) {
        float x = xin[j];
        float sp = (x > 20.f) ? x : log1pf(expf(x));
        r[j] = expf(-ea * sp);
    }
    uint4 pk;
    pk.x = pack2(r[0], r[1]); pk.y = pack2(r[2], r[3]);
    pk.z = pack2(r[4], r[5]); pk.w = pack2(r[6], r[7]);
    unsigned short* dst = dec + ((size_t)(b * NH + h) * NT + t) * 128 + d0;
    *(uint4*)dst = pk;
}

// ---------------------------------------------------------------------------
// beta[b,h,t] = sigmoid(hs[b,t,:] @ b_w[:,h]) — one block per (b,t)
// ---------------------------------------------------------------------------
__global__ __launch_bounds__(256) void beta_k(
    const float* __restrict__ hs, const float* __restrict__ bw,
    float* __restrict__ bt)
{
    __shared__ float sh[ND];
    __shared__ float part[16][17];
    const int m = blockIdx.x, tid = threadIdx.x;
    ((float4*)sh)[tid * 2]     = ((const float4*)(hs + (size_t)m * ND))[tid * 2];
    ((float4*)sh)[tid * 2 + 1] = ((const float4*)(hs + (size_t)m * ND))[tid * 2 + 1];
    __syncthreads();
    const int h = tid & 15, seg = tid >> 4;
    float p = 0.f;
#pragma unroll 8
    for (int j = 0; j < 128; j++)
        p += sh[seg * 128 + j] * bw[(size_t)(seg * 128 + j) * 16 + h];
    part[seg][h] = p;
    __syncthreads();
    if (tid < 16) {
        float s = 0.f;
#pragma unroll
        for (int i = 0; i < 16; i++) s += part[i][tid];
        const int t = m & (NT - 1), b = m >> 12;
        bt[(size_t)(b * NH + tid) * NT + t] = sigmoidf_(s);
    }
}

// ---------------------------------------------------------------------------
// qk[bh,t] = q . k  on bf16 inputs (for the o = q·S_dec + (q·k)·be trick)
// ---------------------------------------------------------------------------
__global__ __launch_bounds__(256) void qk_dot(
    const unsigned short* __restrict__ qn, const unsigned short* __restrict__ kn,
    float* __restrict__ qkd)
{
    const int tid = threadIdx.x;
    const size_t row = (size_t)blockIdx.x * 16 + (tid >> 4);
    const int l = tid & 15;
    uint4 A = *(const uint4*)(qn + row * 128 + l * 8);
    uint4 C = *(const uint4*)(kn + row * 128 + l * 8);
    float p = bf2f(A.x & 0xffff) * bf2f(C.x & 0xffff) + bf2f(A.x >> 16) * bf2f(C.x >> 16)
            + bf2f(A.y & 0xffff) * bf2f(C.y & 0xffff) + bf2f(A.y >> 16) * bf2f(C.y >> 16)
            + bf2f(A.z & 0xffff) * bf2f(C.z & 0xffff) + bf2f(A.z >> 16) * bf2f(C.z >> 16)
            + bf2f(A.w & 0xffff) * bf2f(C.w & 0xffff) + bf2f(A.w >> 16) * bf2f(C.w >> 16);
    p = reduce16f(p);
    if (l == 0) qkd[row] = p;
}

// ---------------------------------------------------------------------------
// Gated delta-rule scan. Grid: BH*8 blocks (one per (b,h,16-col group)),
// 256 threads. Thread (cl=tid>>4, rg=tid&15) owns S[rg*8..+8) of col vg*16+cl.
// bf16 global streams, fp32 in LDS (XOR-swizzled groups), DPP reductions.
// ---------------------------------------------------------------------------
constexpr int SCH = 16;
constexpr int NCHUNK = NT / SCH;  // 256

__global__ __launch_bounds__(256) void kda_scan(
    const unsigned short* __restrict__ qn, const unsigned short* __restrict__ kn,
    const unsigned short* __restrict__ vs, const unsigned short* __restrict__ dc,
    const float* __restrict__ bt, const float* __restrict__ qkd,
    float* __restrict__ osc)
{
    __shared__ float kbuf[2][SCH][128];
    __shared__ float qbuf[2][SCH][128];
    __shared__ float dbuf[2][SCH][128];
    __shared__ float vbuf[2][SCH][16];
    __shared__ float bbuf[2][SCH];
    __shared__ float kqbuf[2][SCH];
    __shared__ float obuf[SCH][16];

    const int tid = threadIdx.x;
    const int vg  = blockIdx.x & 7;
    const int bh  = blockIdx.x >> 3;
    const int bb_ = bh >> 4;
    const int hh  = bh & 15;
    const int cl  = tid >> 4;   // column-in-group (compute) == ss (staging step)
    const int rg  = tid & 15;   // k-row-chunk (compute)     == sg (staging chunk)
    const int glo = swz4(2 * rg) * 4;      // swizzled float offsets (store==load)
    const int ghi = swz4(2 * rg + 1) * 4;

    const int ss = cl;   // staged step index
    const int sg = rg;   // staged row-chunk

    const size_t seqbase = (size_t)bh * NT;

    float S[8];
#pragma unroll
    for (int j = 0; j < 8; j++) S[j] = 0.f;

    uint4 pq, pk, pd;
    unsigned short pv = 0; float pb = 0.f, pqk = 0.f;

    {
        const size_t r = (seqbase + ss) * 128 + sg * 8;
        pq = *(const uint4*)(qn + r);
        pk = *(const uint4*)(kn + r);
        pd = *(const uint4*)(dc + r);
        pv = vs[(seqbase + ss) * 128 + vg * 16 + sg];
        if (tid < SCH) { pb = bt[seqbase + tid]; pqk = qkd[seqbase + tid]; }
        float* qr_ = &qbuf[0][ss][0]; float* kr_ = &kbuf[0][ss][0]; float* dr_ = &dbuf[0][ss][0];
        *(float4*)(qr_ + glo) = bflo(pq); *(float4*)(qr_ + ghi) = bfhi(pq);
        *(float4*)(kr_ + glo) = bflo(pk); *(float4*)(kr_ + ghi) = bfhi(pk);
        *(float4*)(dr_ + glo) = bflo(pd); *(float4*)(dr_ + ghi) = bfhi(pd);
        vbuf[0][ss][sg] = bf2f(pv);
        if (tid < SCH) { bbuf[0][tid] = pb; kqbuf[0][tid] = pqk; }
    }
    __syncthreads();

    int cur = 0;
    for (int cc = 0; cc < NCHUNK; cc++) {
        const int t0 = cc * SCH;
        const bool more = (cc + 1 < NCHUNK);
        if (more) {
            const size_t r = (seqbase + t0 + SCH + ss) * 128 + sg * 8;
            pq = *(const uint4*)(qn + r);
            pk = *(const uint4*)(kn + r);
            pd = *(const uint4*)(dc + r);
            pv = vs[(seqbase + t0 + SCH + ss) * 128 + vg * 16 + sg];
            if (tid < SCH) {
                pb  = bt[seqbase + t0 + SCH + tid];
                pqk = qkd[seqbase + t0 + SCH + tid];
            }
        }
#pragma unroll 4
        for (int s = 0; s < SCH; s++) {
            const float* kr = &kbuf[cur][s][0];
            const float* qr = &qbuf[cur][s][0];
            const float* dr = &dbuf[cur][s][0];
            float4 k0 = *(const float4*)(kr + glo), k1 = *(const float4*)(kr + ghi);
            float4 d0 = *(const float4*)(dr + glo), d1 = *(const float4*)(dr + ghi);
            float4 q0 = *(const float4*)(qr + glo), q1 = *(const float4*)(qr + ghi);
            S[0] *= d0.x; S[1] *= d0.y; S[2] *= d0.z; S[3] *= d0.w;
            S[4] *= d1.x; S[5] *= d1.y; S[6] *= d1.z; S[7] *= d1.w;
            float p1 = k0.x * S[0] + k0.y * S[1] + k0.z * S[2] + k0.w * S[3] +
                       k1.x * S[4] + k1.y * S[5] + k1.z * S[6] + k1.w * S[7];
            float p2 = q0.x * S[0] + q0.y * S[1] + q0.z * S[2] + q0.w * S[3] +
                       q1.x * S[4] + q1.y * S[5] + q1.z * S[6] + q1.w * S[7];
            p1 = reduce16f(p1);
            p2 = reduce16f(p2);
            const float err = vbuf[cur][s][cl] - p1;
            const float be  = bbuf[cur][s] * err;
            S[0] += be * k0.x; S[1] += be * k0.y; S[2] += be * k0.z; S[3] += be * k0.w;
            S[4] += be * k1.x; S[5] += be * k1.y; S[6] += be * k1.z; S[7] += be * k1.w;
            const float ov = p2 + kqbuf[cur][s] * be;  // q·S_new
            if (rg == 0) obuf[s][cl] = ov;
        }
        __syncthreads();
        if (more) {
            const int nxt = cur ^ 1;
            float* qr_ = &qbuf[nxt][ss][0]; float* kr_ = &kbuf[nxt][ss][0]; float* dr_ = &dbuf[nxt][ss][0];
            *(float4*)(qr_ + glo) = bflo(pq); *(float4*)(qr_ + ghi) = bfhi(pq);
            *(float4*)(kr_ + glo) = bflo(pk); *(float4*)(kr_ + ghi) = bfhi(pk);
            *(float4*)(dr_ + glo) = bflo(pd); *(float4*)(dr_ + ghi) = bfhi(pd);
            vbuf[nxt][ss][sg] = bf2f(pv);
            if (tid < SCH) { bbuf[nxt][tid] = pb; kqbuf[nxt][tid] = pqk; }
        }
        osc[((size_t)bb_ * NT + t0 + ss) * ND + hh * 128 + vg * 16 + sg] = obuf[ss][sg];
        __syncthreads();
        cur ^= 1;
    }
}

// ---------------------------------------------------------------------------
// Gated RMSNorm epilogue (in-place on o):
// o = o * rsqrt(mean(o^2)+1e-5) * w * sigmoid(gate + b2)
// ---------------------------------------------------------------------------
__global__ __launch_bounds__(256) void gate_k(
    float* __restrict__ osc, const float* __restrict__ gate,
    const float* __restrict__ gb2, const float* __restrict__ onw)
{
    const int m = blockIdx.x, tid = threadIdx.x;
    const int hd = tid * 8, d0 = hd & 127;
    float* op = osc + (size_t)m * ND + hd;
    float4 o0 = *(const float4*)op, o1 = *(const float4*)(op + 4);
    float ssum = o0.x * o0.x + o0.y * o0.y + o0.z * o0.z + o0.w * o0.w +
                 o1.x * o1.x + o1.y * o1.y + o1.z * o1.z + o1.w * o1.w;
    ssum = reduce16f(ssum);
    const float r = rsqrtf(ssum * (1.0f / 128.0f) + 1e-5f);
    const float* gp = gate + (size_t)m * ND + hd;
    float4 g0 = *(const float4*)gp, g1 = *(const float4*)(gp + 4);
    float4 b0 = *(const float4*)&gb2[hd], b1 = *(const float4*)&gb2[hd + 4];
    float4 w0 = *(const float4*)&onw[d0], w1 = *(const float4*)&onw[d0 + 4];
    float4 r0, r1;
    r0.x = o0.x * r * w0.x * sigmoidf_(g0.x + b0.x);
    r0.y = o0.y * r * w0.y * sigmoidf_(g0.y + b0.y);
    r0.z = o0.z * r * w0.z * sigmoidf_(g0.z + b0.z);
    r0.w = o0.w * r * w0.w * sigmoidf_(g0.w + b0.w);
    r1.x = o1.x * r * w1.x * sigmoidf_(g1.x + b1.x);
    r1.y = o1.y * r * w1.y * sigmoidf_(g1.y + b1.y);
    r1.z = o1.z * r * w1.z * sigmoidf_(g1.z + b1.z);
    r1.w = o1.w * r * w1.w * sigmoidf_(g1.w + b1.w);
    *(float4*)op       = r0;
    *(float4*)(op + 4) = r1;
}

// Diagnostic: encode ws_size (MB) into output if workspace too small.
__global__ void diag_fill(float* out, float val, int n) {
    for (int i = blockIdx.x * blockDim.x + threadIdx.x; i < n; i += gridDim.x * blockDim.x)
        out[i] = val;
}

// ---------------------------------------------------------------------------
extern "C" void kernel_launch(void* const* d_in, const int* in_sizes, int n_in,
                              void* d_out, int out_size, void* d_ws, size_t ws_size,
                              hipStream_t stream)
{
    const float* hs    = (const float*)d_in[0];
    const float* q_w   = (const float*)d_in[1];
    const float* k_w   = (const float*)d_in[2];
    const float* v_w   = (const float*)d_in[3];
    const float* qcw   = (const float*)d_in[4];
    const float* kcw   = (const float*)d_in[5];
    const float* vcw   = (const float*)d_in[6];
    const float* f_w1  = (const float*)d_in[7];
    const float* f_w2  = (const float*)d_in[8];
    const float* b_w   = (const float*)d_in[9];
    const float* A_log = (const float*)d_in[10];
    const float* dt_b  = (const float*)d_in[11];
    const float* g_w1  = (const float*)d_in[12];
    const float* g_w2  = (const float*)d_in[13];
    const float* g_b2  = (const float*)d_in[14];
    const float* onw   = (const float*)d_in[15];
    const float* o_w   = (const float*)d_in[16];
    float* out = (float*)d_out;

    // ---- workspace layout (bytes) -----------------------------------------
    const size_t SEQ  = (size_t)BHN * NT;          // 131072 rows
    const size_t BF   = SEQ * 128 * 2;             // one bf16 stream: 32 MiB
    char* wsb = (char*)d_ws;
    size_t off = 0;
    unsigned short* qn = (unsigned short*)(wsb + off); off += BF;
    unsigned short* kn = (unsigned short*)(wsb + off); off += BF;
    unsigned short* vv = (unsigned short*)(wsb + off); off += BF;
    unsigned short* dc = (unsigned short*)(wsb + off); off += BF;
    float* OBUF = (float*)(wsb + off); off += (size_t)MROWS * ND * 4;   // 64 MiB
    float* f1   = (float*)(wsb + off); off += (size_t)MROWS * DK * 4;   // 4 MiB
    float* g1   = (float*)(wsb + off); off += (size_t)MROWS * DK * 4;   // 4 MiB
    float* bt   = (float*)(wsb + off); off += SEQ * 4;                  // 0.5 MiB
    float* qk   = (float*)(wsb + off); off += SEQ * 4;                  // 0.5 MiB
    // P2 (gate preact, 64 MiB fp32) aliases the dead qn/kn region post-scan
    float* P2 = (float*)wsb;
    // P1 (GEMM preact scratch, 64 MiB fp32) is d_out itself (all uses pre-scan)
    float* P1 = out;

    if (ws_size < off) {  // diagnostic: absmax will read ~1e6 + ws_MB
        diag_fill<<<512, 256, 0, stream>>>(out, 1.0e6f + (float)(ws_size >> 20),
                                           out_size);
        return;
    }

    dim3 blk(256);
    auto ggrid = [](int Md, int Nd) { return dim3((unsigned)((Md / 128) * (Nd / 128))); };

    // 1. projections + conv/silu(/l2norm), transposed into scan layout (bf16)
    gemm_f32<<<ggrid(MROWS, ND), blk, 0, stream>>>(hs, q_w, P1, MROWS, ND, ND);
    conv_silu<2><<<MROWS, blk, 0, stream>>>(P1, qcw, qn);
    gemm_f32<<<ggrid(MROWS, ND), blk, 0, stream>>>(hs, k_w, P1, MROWS, ND, ND);
    conv_silu<1><<<MROWS, blk, 0, stream>>>(P1, kcw, kn);
    gemm_f32<<<ggrid(MROWS, ND), blk, 0, stream>>>(hs, v_w, P1, MROWS, ND, ND);
    conv_silu<0><<<MROWS, blk, 0, stream>>>(P1, vcw, vv);

    // 2. decay path: g = (hs@f_w1)@f_w2 -> exp(-exp(A_log)*softplus(g+dt_bias))
    gemm_f32<<<ggrid(MROWS, DK), blk, 0, stream>>>(hs, f_w1, f1, MROWS, DK, ND);
    gemm_f32<<<ggrid(MROWS, ND), blk, 0, stream>>>(f1, f_w2, P1, MROWS, ND, DK);
    decay_k<<<MROWS, blk, 0, stream>>>(P1, A_log, dt_b, dc);

    // 3. gate 1st GEMM (2nd one runs post-scan into P2)
    gemm_f32<<<ggrid(MROWS, DK), blk, 0, stream>>>(hs, g_w1, g1, MROWS, DK, ND);

    // 4. beta + q.k precompute
    beta_k<<<MROWS, blk, 0, stream>>>(hs, b_w, bt);
    qk_dot<<<BHN * NT / 16, blk, 0, stream>>>(qn, kn, qk);

    // 5. scan -> OBUF [B,T,H*Dv] fp32
    kda_scan<<<BHN * 8, blk, 0, stream>>>(qn, kn, vv, dc, bt, qk, OBUF);

    // 6. gate preact into P2 (bf16 region now dead), gated RMSNorm in-place
    gemm_f32<<<ggrid(MROWS, ND), blk, 0, stream>>>(g1, g_w2, P2, MROWS, ND, DK);
    gate_k<<<MROWS, blk, 0, stream>>>(OBUF, P2, g_b2, onw);

    // 7. final projection
    gemm_f32<<<ggrid(MROWS, ND), blk, 0, stream>>>(OBUF, o_w, out, MROWS, ND, ND);
}

// Round 4
// 1667.388 us; speedup vs baseline: 3.1530x; 3.1530x over previous
//
#include <hip/hip_runtime.h>
#include <math.h>

// ---------------------------------------------------------------------------
// KimiDeltaAttention forward, MI355X. Round 4: bf16 MFMA GEMMs (m97 structure)
// replace fp32 vector GEMMs. Scan unchanged from passing round 3.
// Shapes fixed: B=2, T=4096, D=2048, H=16, Dk=Dv=128.
// ---------------------------------------------------------------------------

constexpr int NB = 2, NT = 4096, ND = 2048, NH = 16, DK = 128, DV = 128;
constexpr int MROWS = NB * NT;   // 8192
constexpr int BHN   = NB * NH;   // 32

#define DEV static __device__ __forceinline__

typedef __attribute__((ext_vector_type(8))) short short8;   // bf16x8 MFMA frag
typedef __attribute__((ext_vector_type(4))) float f32x4;    // MFMA acc frag

DEV float sigmoidf_(float x) { return 1.0f / (1.0f + expf(-x)); }

DEV float bf2f(unsigned u) { return __uint_as_float(u << 16); }
DEV unsigned f2bf(float f) {  // round-to-nearest-even
    unsigned u = __float_as_uint(f);
    return (u + 0x7fffu + ((u >> 16) & 1u)) >> 16;
}
DEV unsigned pack2(float a, float b) { return f2bf(a) | (f2bf(b) << 16); }

// async global->LDS, 16B per lane (dst = wave-uniform base + lane*16)
DEV void gl2lds16(const unsigned short* g, unsigned short* l) {
    __builtin_amdgcn_global_load_lds(
        (const __attribute__((address_space(1))) unsigned int*)g,
        (__attribute__((address_space(3))) unsigned int*)l, 16, 0, 0);
}

// 16-lane butterfly sum via DPP (VALU pipe; groups = 16 consecutive lanes)
template <int CTRL>
DEV float dppadd(float x) {
    int y = __builtin_amdgcn_mov_dpp(__float_as_int(x), CTRL, 0xF, 0xF, true);
    return x + __int_as_float(y);
}
DEV float reduce16f(float x) {
    x = dppadd<0xB1>(x);   // quad_perm xor1
    x = dppadd<0x4E>(x);   // quad_perm xor2
    x = dppadd<0x141>(x);  // row_half_mirror
    x = dppadd<0x140>(x);  // row_mirror
    return x;
}

// Bijective XOR swizzle on float4-group index p in [0,32): p' = p ^ (p>>3).
DEV int swz4(int p) { return p ^ (p >> 3); }

DEV float4 bflo(uint4 U) {
    return make_float4(bf2f(U.x & 0xffff), bf2f(U.x >> 16),
                       bf2f(U.y & 0xffff), bf2f(U.y >> 16));
}
DEV float4 bfhi(uint4 U) {
    return make_float4(bf2f(U.z & 0xffff), bf2f(U.z >> 16),
                       bf2f(U.w & 0xffff), bf2f(U.w >> 16));
}

// ---------------------------------------------------------------------------
// bf16 MFMA GEMM: C[M,N] = A[M,K] @ Bt[N,K]^T. A,Bt bf16 row-major
// (K contiguous). Tile 128x128, BK=64, 256 threads (4 waves, 2x2 of 64x64).
// LDS linear [128 rows][8 slots of 8 bf16], slot XOR-swizzled via pre-swizzled
// global source (rule #21). OUTBF: 1 = bf16 out, 0 = f32 out.
// Requires M%128==0, N%128==0, K%64==0.
// ---------------------------------------------------------------------------
template <int OUTBF>
__global__ __launch_bounds__(256) void gemm_bf16(
    const unsigned short* __restrict__ A, const unsigned short* __restrict__ Bt,
    void* __restrict__ Cv, int Md, int Nd, int Kd)
{
    __shared__ unsigned short As[128 * 64];
    __shared__ unsigned short Bs[128 * 64];

    const int nbx = Nd >> 7;
    const int bx = blockIdx.x % nbx;
    const int by = blockIdx.x / nbx;
    const int m0 = by << 7, n0 = bx << 7;
    const int tid = threadIdx.x;
    const int lane = tid & 63, wid = tid >> 6;
    const int wr = wid >> 1, wc = wid & 1;

    // staging: issue i covers rows i*32 + tid/8; slot pre-swizzled by row&7
    const int srow  = tid >> 3;
    const int sslot = (tid & 7) ^ (srow & 7);
    const unsigned short* ag = A  + (size_t)(m0 + srow) * Kd + sslot * 8;
    const unsigned short* bg = Bt + (size_t)(n0 + srow) * Kd + sslot * 8;
    const size_t rstep32 = (size_t)32 * Kd;
    unsigned short* aw = As + wid * 512;  // wave-uniform LDS base (+i*2048)
    unsigned short* bw = Bs + wid * 512;

    // fragment read coords
    const int rrow  = lane & 15;
    const int khalf = lane >> 4;
    const int rswz  = rrow & 7;

    f32x4 zf = {0.f, 0.f, 0.f, 0.f};
    f32x4 acc[4][4];
#pragma unroll
    for (int m = 0; m < 4; m++)
#pragma unroll
        for (int n = 0; n < 4; n++) acc[m][n] = zf;

    for (int k0 = 0; k0 < Kd; k0 += 64) {
#pragma unroll
        for (int i = 0; i < 4; i++) {
            gl2lds16(ag + (size_t)i * rstep32 + k0, aw + i * 2048);
            gl2lds16(bg + (size_t)i * rstep32 + k0, bw + i * 2048);
        }
        __syncthreads();   // drain loads; LDS ready
#pragma unroll
        for (int kk = 0; kk < 2; kk++) {
            const int slot = (kk * 4 + khalf) ^ rswz;
            short8 a[4], b[4];
#pragma unroll
            for (int m = 0; m < 4; m++)
                a[m] = *(const short8*)&As[(wr * 64 + m * 16 + rrow) * 64 + slot * 8];
#pragma unroll
            for (int n = 0; n < 4; n++)
                b[n] = *(const short8*)&Bs[(wc * 64 + n * 16 + rrow) * 64 + slot * 8];
#pragma unroll
            for (int m = 0; m < 4; m++)
#pragma unroll
                for (int n = 0; n < 4; n++)
                    acc[m][n] = __builtin_amdgcn_mfma_f32_16x16x32_bf16(
                        a[m], b[n], acc[m][n], 0, 0, 0);
        }
        __syncthreads();   // all reads done before next stage overwrites
    }

    // epilogue: D col = lane&15, row = (lane>>4)*4 + reg
#pragma unroll
    for (int m = 0; m < 4; m++) {
        const int rowb = m0 + wr * 64 + m * 16 + khalf * 4;
#pragma unroll
        for (int n = 0; n < 4; n++) {
            const int col = n0 + wc * 64 + n * 16 + rrow;
#pragma unroll
            for (int r = 0; r < 4; r++) {
                const float v = acc[m][n][r];
                if (OUTBF)
                    ((unsigned short*)Cv)[(size_t)(rowb + r) * Nd + col] =
                        (unsigned short)f2bf(v);
                else
                    ((float*)Cv)[(size_t)(rowb + r) * Nd + col] = v;
            }
        }
    }
}

// ---------------------------------------------------------------------------
// Weight transpose + bf16 convert: W[Kd,Nd] f32 -> Wt[Nd,Kd] bf16. 64x64 tiles.
// ---------------------------------------------------------------------------
__global__ __launch_bounds__(256) void wtrans(
    const float* __restrict__ W, unsigned short* __restrict__ Wt, int Kd, int Nd)
{
    __shared__ float T[64][65];
    const int nbk = Kd >> 6;
    const int bk = blockIdx.x % nbk, bn = blockIdx.x / nbk;
    const int k0 = bk << 6, n0 = bn << 6;
    const int tid = threadIdx.x;
    {
        const int r = tid >> 2, cg = tid & 3;
#pragma unroll
        for (int i = 0; i < 4; i++) {
            float4 f = *(const float4*)&W[(size_t)(k0 + r) * Nd + n0 + cg * 16 + i * 4];
            T[r][cg * 16 + i * 4 + 0] = f.x;
            T[r][cg * 16 + i * 4 + 1] = f.y;
            T[r][cg * 16 + i * 4 + 2] = f.z;
            T[r][cg * 16 + i * 4 + 3] = f.w;
        }
    }
    __syncthreads();
    {
        const int n = tid >> 2, kg = tid & 3;
#pragma unroll
        for (int i = 0; i < 2; i++) {
            unsigned o[4];
#pragma unroll
            for (int j = 0; j < 4; j++) {
                const int kk = kg * 16 + i * 8 + 2 * j;
                o[j] = pack2(T[kk][n], T[kk + 1][n]);
            }
            *(uint4*)&Wt[(size_t)(n0 + n) * Kd + k0 + kg * 16 + i * 8] =
                make_uint4(o[0], o[1], o[2], o[3]);
        }
    }
}

// f32 -> bf16 bulk convert (8 elems/thread)
__global__ __launch_bounds__(256) void f2bf_k(
    const float* __restrict__ x, unsigned short* __restrict__ y, int n8)
{
    const int i = blockIdx.x * blockDim.x + threadIdx.x;
    if (i < n8) {
        float4 a = *(const float4*)&x[(size_t)i * 8];
        float4 b = *(const float4*)&x[(size_t)i * 8 + 4];
        uint4 o = make_uint4(pack2(a.x, a.y), pack2(a.z, a.w),
                             pack2(b.x, b.y), pack2(b.z, b.w));
        *(uint4*)&y[(size_t)i * 8] = o;
    }
}

// ---------------------------------------------------------------------------
// Causal depthwise conv (K=4) + silu, optional l2norm (+q scale).
// in: pre [B*T, 2048] BF16; w [2048,4] f32; out transposed [B*H, T, 128] BF16.
// MODE: 0 = silu only (v), 1 = +l2norm (k), 2 = +l2norm*Dk^-0.5 (q).
// ---------------------------------------------------------------------------
template <int MODE>
__global__ __launch_bounds__(256) void conv_silu(
    const unsigned short* __restrict__ pre, const float* __restrict__ cw,
    unsigned short* __restrict__ outp)
{
    const int m = blockIdx.x;
    const int t = m & (NT - 1);
    const int b = m >> 12;
    const int tid = threadIdx.x;
    const int hd = tid * 8;
    const int h  = hd >> 7;
    const int d0 = hd & 127;

    float xr[4][8];
#pragma unroll
    for (int i = 0; i < 4; i++) {
        const int tt = t - 3 + i;
        if (tt >= 0) {
            uint4 u = *(const uint4*)(pre + (size_t)(m - 3 + i) * ND + hd);
            float4 lo = bflo(u), hi = bfhi(u);
            xr[i][0] = lo.x; xr[i][1] = lo.y; xr[i][2] = lo.z; xr[i][3] = lo.w;
            xr[i][4] = hi.x; xr[i][5] = hi.y; xr[i][6] = hi.z; xr[i][7] = hi.w;
        } else {
#pragma unroll
            for (int j = 0; j < 8; j++) xr[i][j] = 0.f;
        }
    }
    float y[8];
    float ssum = 0.f;
#pragma unroll
    for (int j = 0; j < 8; j++) {
        float4 w = *(const float4*)&cw[(size_t)(hd + j) * 4];
        float v = xr[0][j] * w.x + xr[1][j] * w.y + xr[2][j] * w.z + xr[3][j] * w.w;
        v = v * sigmoidf_(v);  // silu
        y[j] = v;
        ssum += v * v;
    }
    float scale = 1.f;
    if (MODE >= 1) {
        ssum = reduce16f(ssum);
        scale = rsqrtf(ssum + 1e-6f);
        if (MODE == 2) scale *= 0.08838834764831845f;  // Dk^-0.5
    }
    uint4 pk;
    pk.x = pack2(y[0] * scale, y[1] * scale);
    pk.y = pack2(y[2] * scale, y[3] * scale);
    pk.z = pack2(y[4] * scale, y[5] * scale);
    pk.w = pack2(y[6] * scale, y[7] * scale);
    unsigned short* dst = outp + ((size_t)(b * NH + h) * NT + t) * 128 + d0;
    *(uint4*)dst = pk;
}

// ---------------------------------------------------------------------------
// decay[b,h,t,d] = exp(-exp(A_log[h]) * softplus(g + dt_bias)), bf16 in/out
// ---------------------------------------------------------------------------
__global__ __launch_bounds__(256) void decay_k(
    const unsigned short* __restrict__ g, const float* __restrict__ A_log,
    const float* __restrict__ dtb, unsigned short* __restrict__ dec)
{
    const int m = blockIdx.x;
    const int t = m & (NT - 1);
    const int b = m >> 12;
    const int tid = threadIdx.x;
    const int hd = tid * 8, h = hd >> 7, d0 = hd & 127;
    const float ea = expf(A_log[h]);
    uint4 u = *(const uint4*)(g + (size_t)m * ND + hd);
    float4 lo = bflo(u), hi = bfhi(u);
    float4 b0 = *(const float4*)&dtb[hd], b1 = *(const float4*)&dtb[hd + 4];
    float xin[8] = {lo.x + b0.x, lo.y + b0.y, lo.z + b0.z, lo.w + b0.w,
                    hi.x + b1.x, hi.y + b1.y, hi.z + b1.z, hi.w + b1.w};
    float r[8];
#pragma unroll
    for (int j = 0; j < 8; j++) {
        float x = xin[j];
        float sp = (x > 20.f) ? x : log1pf(expf(x));
        r[j] = expf(-ea * sp);
    }
    uint4 pk;
    pk.x = pack2(r[0], r[1]); pk.y = pack2(r[2], r[3]);
    pk.z = pack2(r[4], r[5]); pk.w = pack2(r[6], r[7]);
    unsigned short* dst = dec + ((size_t)(b * NH + h) * NT + t) * 128 + d0;
    *(uint4*)dst = pk;
}

// ---------------------------------------------------------------------------
// beta[b,h,t] = sigmoid(hs[b,t,:] @ b_w[:,h]) — one block per (b,t); fp32 hs
// ---------------------------------------------------------------------------
__global__ __launch_bounds__(256) void beta_k(
    const float* __restrict__ hs, const float* __restrict__ bw,
    float* __restrict__ bt)
{
    __shared__ float sh[ND];
    __shared__ float part[16][17];
    const int m = blockIdx.x, tid = threadIdx.x;
    ((float4*)sh)[tid * 2]     = ((const float4*)(hs + (size_t)m * ND))[tid * 2];
    ((float4*)sh)[tid * 2 + 1] = ((const float4*)(hs + (size_t)m * ND))[tid * 2 + 1];
    __syncthreads();
    const int h = tid & 15, seg = tid >> 4;
    float p = 0.f;
#pragma unroll 8
    for (int j = 0; j < 128; j++)
        p += sh[seg * 128 + j] * bw[(size_t)(seg * 128 + j) * 16 + h];
    part[seg][h] = p;
    __syncthreads();
    if (tid < 16) {
        float s = 0.f;
#pragma unroll
        for (int i = 0; i < 16; i++) s += part[i][tid];
        const int t = m & (NT - 1), b = m >> 12;
        bt[(size_t)(b * NH + tid) * NT + t] = sigmoidf_(s);
    }
}

// ---------------------------------------------------------------------------
// qk[bh,t] = q . k  on bf16 inputs (for the o = q·S_dec + (q·k)·be trick)
// ---------------------------------------------------------------------------
__global__ __launch_bounds__(256) void qk_dot(
    const unsigned short* __restrict__ qn, const unsigned short* __restrict__ kn,
    float* __restrict__ qkd)
{
    const int tid = threadIdx.x;
    const size_t row = (size_t)blockIdx.x * 16 + (tid >> 4);
    const int l = tid & 15;
    uint4 A = *(const uint4*)(qn + row * 128 + l * 8);
    uint4 C = *(const uint4*)(kn + row * 128 + l * 8);
    float4 al = bflo(A), ah = bfhi(A), cl_ = bflo(C), ch = bfhi(C);
    float p = al.x * cl_.x + al.y * cl_.y + al.z * cl_.z + al.w * cl_.w +
              ah.x * ch.x + ah.y * ch.y + ah.z * ch.z + ah.w * ch.w;
    p = reduce16f(p);
    if (l == 0) qkd[row] = p;
}

// ---------------------------------------------------------------------------
// Gated delta-rule scan (unchanged from passing round 3).
// ---------------------------------------------------------------------------
constexpr int SCH = 16;
constexpr int NCHUNK = NT / SCH;  // 256

__global__ __launch_bounds__(256) void kda_scan(
    const unsigned short* __restrict__ qn, const unsigned short* __restrict__ kn,
    const unsigned short* __restrict__ vs, const unsigned short* __restrict__ dc,
    const float* __restrict__ bt, const float* __restrict__ qkd,
    float* __restrict__ osc)
{
    __shared__ float kbuf[2][SCH][128];
    __shared__ float qbuf[2][SCH][128];
    __shared__ float dbuf[2][SCH][128];
    __shared__ float vbuf[2][SCH][16];
    __shared__ float bbuf[2][SCH];
    __shared__ float kqbuf[2][SCH];
    __shared__ float obuf[SCH][16];

    const int tid = threadIdx.x;
    const int vg  = blockIdx.x & 7;
    const int bh  = blockIdx.x >> 3;
    const int bb_ = bh >> 4;
    const int hh  = bh & 15;
    const int cl  = tid >> 4;
    const int rg  = tid & 15;
    const int glo = swz4(2 * rg) * 4;
    const int ghi = swz4(2 * rg + 1) * 4;

    const int ss = cl;
    const int sg = rg;

    const size_t seqbase = (size_t)bh * NT;

    float S[8];
#pragma unroll
    for (int j = 0; j < 8; j++) S[j] = 0.f;

    uint4 pq, pk, pd;
    unsigned short pv = 0; float pb = 0.f, pqk = 0.f;

    {
        const size_t r = (seqbase + ss) * 128 + sg * 8;
        pq = *(const uint4*)(qn + r);
        pk = *(const uint4*)(kn + r);
        pd = *(const uint4*)(dc + r);
        pv = vs[(seqbase + ss) * 128 + vg * 16 + sg];
        if (tid < SCH) { pb = bt[seqbase + tid]; pqk = qkd[seqbase + tid]; }
        float* qr_ = &qbuf[0][ss][0]; float* kr_ = &kbuf[0][ss][0]; float* dr_ = &dbuf[0][ss][0];
        *(float4*)(qr_ + glo) = bflo(pq); *(float4*)(qr_ + ghi) = bfhi(pq);
        *(float4*)(kr_ + glo) = bflo(pk); *(float4*)(kr_ + ghi) = bfhi(pk);
        *(float4*)(dr_ + glo) = bflo(pd); *(float4*)(dr_ + ghi) = bfhi(pd);
        vbuf[0][ss][sg] = bf2f(pv);
        if (tid < SCH) { bbuf[0][tid] = pb; kqbuf[0][tid] = pqk; }
    }
    __syncthreads();

    int cur = 0;
    for (int cc = 0; cc < NCHUNK; cc++) {
        const int t0 = cc * SCH;
        const bool more = (cc + 1 < NCHUNK);
        if (more) {
            const size_t r = (seqbase + t0 + SCH + ss) * 128 + sg * 8;
            pq = *(const uint4*)(qn + r);
            pk = *(const uint4*)(kn + r);
            pd = *(const uint4*)(dc + r);
            pv = vs[(seqbase + t0 + SCH + ss) * 128 + vg * 16 + sg];
            if (tid < SCH) {
                pb  = bt[seqbase + t0 + SCH + tid];
                pqk = qkd[seqbase + t0 + SCH + tid];
            }
        }
#pragma unroll 4
        for (int s = 0; s < SCH; s++) {
            const float* kr = &kbuf[cur][s][0];
            const float* qr = &qbuf[cur][s][0];
            const float* dr = &dbuf[cur][s][0];
            float4 k0 = *(const float4*)(kr + glo), k1 = *(const float4*)(kr + ghi);
            float4 d0 = *(const float4*)(dr + glo), d1 = *(const float4*)(dr + ghi);
            float4 q0 = *(const float4*)(qr + glo), q1 = *(const float4*)(qr + ghi);
            S[0] *= d0.x; S[1] *= d0.y; S[2] *= d0.z; S[3] *= d0.w;
            S[4] *= d1.x; S[5] *= d1.y; S[6] *= d1.z; S[7] *= d1.w;
            float p1 = k0.x * S[0] + k0.y * S[1] + k0.z * S[2] + k0.w * S[3] +
                       k1.x * S[4] + k1.y * S[5] + k1.z * S[6] + k1.w * S[7];
            float p2 = q0.x * S[0] + q0.y * S[1] + q0.z * S[2] + q0.w * S[3] +
                       q1.x * S[4] + q1.y * S[5] + q1.z * S[6] + q1.w * S[7];
            p1 = reduce16f(p1);
            p2 = reduce16f(p2);
            const float err = vbuf[cur][s][cl] - p1;
            const float be  = bbuf[cur][s] * err;
            S[0] += be * k0.x; S[1] += be * k0.y; S[2] += be * k0.z; S[3] += be * k0.w;
            S[4] += be * k1.x; S[5] += be * k1.y; S[6] += be * k1.z; S[7] += be * k1.w;
            const float ov = p2 + kqbuf[cur][s] * be;
            if (rg == 0) obuf[s][cl] = ov;
        }
        __syncthreads();
        if (more) {
            const int nxt = cur ^ 1;
            float* qr_ = &qbuf[nxt][ss][0]; float* kr_ = &kbuf[nxt][ss][0]; float* dr_ = &dbuf[nxt][ss][0];
            *(float4*)(qr_ + glo) = bflo(pq); *(float4*)(qr_ + ghi) = bfhi(pq);
            *(float4*)(kr_ + glo) = bflo(pk); *(float4*)(kr_ + ghi) = bfhi(pk);
            *(float4*)(dr_ + glo) = bflo(pd); *(float4*)(dr_ + ghi) = bfhi(pd);
            vbuf[nxt][ss][sg] = bf2f(pv);
            if (tid < SCH) { bbuf[nxt][tid] = pb; kqbuf[nxt][tid] = pqk; }
        }
        osc[((size_t)bb_ * NT + t0 + ss) * ND + hh * 128 + vg * 16 + sg] = obuf[ss][sg];
        __syncthreads();
        cur ^= 1;
    }
}

// ---------------------------------------------------------------------------
// Gated RMSNorm epilogue: ogb = bf16( o*rsqrt(mean o^2+1e-5)*w*sig(gate+b2) )
// o fp32, gate bf16, out bf16.
// ---------------------------------------------------------------------------
__global__ __launch_bounds__(256) void gate_k(
    const float* __restrict__ osc, const unsigned short* __restrict__ gateb,
    const float* __restrict__ gb2, const float* __restrict__ onw,
    unsigned short* __restrict__ ogb)
{
    const int m = blockIdx.x, tid = threadIdx.x;
    const int hd = tid * 8, d0 = hd & 127;
    const float* op = osc + (size_t)m * ND + hd;
    float4 o0 = *(const float4*)op, o1 = *(const float4*)(op + 4);
    float ssum = o0.x * o0.x + o0.y * o0.y + o0.z * o0.z + o0.w * o0.w +
                 o1.x * o1.x + o1.y * o1.y + o1.z * o1.z + o1.w * o1.w;
    ssum = reduce16f(ssum);
    const float r = rsqrtf(ssum * (1.0f / 128.0f) + 1e-5f);
    uint4 gu = *(const uint4*)(gateb + (size_t)m * ND + hd);
    float4 gl = bflo(gu), gh = bfhi(gu);
    float4 b0 = *(const float4*)&gb2[hd], b1 = *(const float4*)&gb2[hd + 4];
    float4 w0 = *(const float4*)&onw[d0], w1 = *(const float4*)&onw[d0 + 4];
    float res[8];
    res[0] = o0.x * r * w0.x * sigmoidf_(gl.x + b0.x);
    res[1] = o0.y * r * w0.y * sigmoidf_(gl.y + b0.y);
    res[2] = o0.z * r * w0.z * sigmoidf_(gl.z + b0.z);
    res[3] = o0.w * r * w0.w * sigmoidf_(gl.w + b0.w);
    res[4] = o1.x * r * w1.x * sigmoidf_(gh.x + b1.x);
    res[5] = o1.y * r * w1.y * sigmoidf_(gh.y + b1.y);
    res[6] = o1.z * r * w1.z * sigmoidf_(gh.z + b1.z);
    res[7] = o1.w * r * w1.w * sigmoidf_(gh.w + b1.w);
    uint4 pk;
    pk.x = pack2(res[0], res[1]); pk.y = pack2(res[2], res[3]);
    pk.z = pack2(res[4], res[5]); pk.w = pack2(res[6], res[7]);
    *(uint4*)(ogb + (size_t)m * ND + hd) = pk;
}

// Diagnostic: encode ws_size (MB) into output if workspace too small.
__global__ void diag_fill(float* out, float val, int n) {
    for (int i = blockIdx.x * blockDim.x + threadIdx.x; i < n; i += gridDim.x * blockDim.x)
        out[i] = val;
}

// ---------------------------------------------------------------------------
extern "C" void kernel_launch(void* const* d_in, const int* in_sizes, int n_in,
                              void* d_out, int out_size, void* d_ws, size_t ws_size,
                              hipStream_t stream)
{
    const float* hs    = (const float*)d_in[0];
    const float* q_w   = (const float*)d_in[1];
    const float* k_w   = (const float*)d_in[2];
    const float* v_w   = (const float*)d_in[3];
    const float* qcw   = (const float*)d_in[4];
    const float* kcw   = (const float*)d_in[5];
    const float* vcw   = (const float*)d_in[6];
    const float* f_w1  = (const float*)d_in[7];
    const float* f_w2  = (const float*)d_in[8];
    const float* b_w   = (const float*)d_in[9];
    const float* A_log = (const float*)d_in[10];
    const float* dt_b  = (const float*)d_in[11];
    const float* g_w1  = (const float*)d_in[12];
    const float* g_w2  = (const float*)d_in[13];
    const float* g_b2  = (const float*)d_in[14];
    const float* onw   = (const float*)d_in[15];
    const float* o_w   = (const float*)d_in[16];
    float* out = (float*)d_out;

    // ---- workspace layout (bytes), peak 175 MB ----------------------------
    const size_t SEQ = (size_t)BHN * NT;           // 131072
    const size_t BF  = SEQ * 128 * 2;              // bf16 stream: 32 MiB
    char* wsb = (char*)d_ws;
    size_t off = 0;
    unsigned short* qn   = (unsigned short*)(wsb + off); off += BF;
    unsigned short* kn   = (unsigned short*)(wsb + off); off += BF;
    unsigned short* vv   = (unsigned short*)(wsb + off); off += BF;  // ogb post-scan
    unsigned short* dc   = (unsigned short*)(wsb + off); off += BF;
    unsigned short* P1   = (unsigned short*)(wsb + off); off += (size_t)MROWS * ND * 2; // 32 MiB
    unsigned short* WT   = (unsigned short*)(wsb + off); off += (size_t)ND * ND * 2;    // 8 MiB
    unsigned short* fw1t = (unsigned short*)(wsb + off); off += (size_t)DK * ND * 2;
    unsigned short* fw2t = (unsigned short*)(wsb + off); off += (size_t)ND * DK * 2;
    unsigned short* gw1t = (unsigned short*)(wsb + off); off += (size_t)DK * ND * 2;
    unsigned short* gw2t = (unsigned short*)(wsb + off); off += (size_t)ND * DK * 2;
    unsigned short* f1b  = (unsigned short*)(wsb + off); off += (size_t)MROWS * DK * 2;
    unsigned short* g1b  = (unsigned short*)(wsb + off); off += (size_t)MROWS * DK * 2;
    float* bt = (float*)(wsb + off); off += SEQ * 4;
    float* qk = (float*)(wsb + off); off += SEQ * 4;
    unsigned short* ogb = vv;                      // alias: vv dead post-scan
    unsigned short* hsb = (unsigned short*)d_out;  // alias: d_out free pre-scan

    if (ws_size < off) {
        diag_fill<<<512, 256, 0, stream>>>(out, 1.0e6f + (float)(ws_size >> 20), out_size);
        return;
    }

    dim3 blk(256);
    auto g2 = [](int Md, int Nd) { return dim3((unsigned)((Md >> 7) * (Nd >> 7))); };
    auto gt = [](int Kd, int Nd) { return dim3((unsigned)((Kd >> 6) * (Nd >> 6))); };

    // 0. hs -> bf16 (staged in d_out; dead before scan overwrites)
    f2bf_k<<<(MROWS * ND / 8 + 255) / 256, blk, 0, stream>>>(hs, hsb, MROWS * ND / 8);

    // 1. q/k/v projections (bf16 MFMA) + conv/silu(/l2norm) into scan layout
    wtrans<<<gt(ND, ND), blk, 0, stream>>>(q_w, WT, ND, ND);
    gemm_bf16<1><<<g2(MROWS, ND), blk, 0, stream>>>(hsb, WT, P1, MROWS, ND, ND);
    conv_silu<2><<<MROWS, blk, 0, stream>>>(P1, qcw, qn);
    wtrans<<<gt(ND, ND), blk, 0, stream>>>(k_w, WT, ND, ND);
    gemm_bf16<1><<<g2(MROWS, ND), blk, 0, stream>>>(hsb, WT, P1, MROWS, ND, ND);
    conv_silu<1><<<MROWS, blk, 0, stream>>>(P1, kcw, kn);
    wtrans<<<gt(ND, ND), blk, 0, stream>>>(v_w, WT, ND, ND);
    gemm_bf16<1><<<g2(MROWS, ND), blk, 0, stream>>>(hsb, WT, P1, MROWS, ND, ND);
    conv_silu<0><<<MROWS, blk, 0, stream>>>(P1, vcw, vv);

    // 2. decay path: g = (hs@f_w1)@f_w2 -> exp(-exp(A_log)*softplus(g+dt_bias))
    wtrans<<<gt(ND, DK), blk, 0, stream>>>(f_w1, fw1t, ND, DK);
    gemm_bf16<1><<<g2(MROWS, DK), blk, 0, stream>>>(hsb, fw1t, f1b, MROWS, DK, ND);
    wtrans<<<gt(DK, ND), blk, 0, stream>>>(f_w2, fw2t, DK, ND);
    gemm_bf16<1><<<g2(MROWS, ND), blk, 0, stream>>>(f1b, fw2t, P1, MROWS, ND, DK);
    decay_k<<<MROWS, blk, 0, stream>>>(P1, A_log, dt_b, dc);

    // 3. output gate preact -> P1 (bf16; survives scan, consumed by gate_k)
    wtrans<<<gt(ND, DK), blk, 0, stream>>>(g_w1, gw1t, ND, DK);
    gemm_bf16<1><<<g2(MROWS, DK), blk, 0, stream>>>(hsb, gw1t, g1b, MROWS, DK, ND);
    wtrans<<<gt(DK, ND), blk, 0, stream>>>(g_w2, gw2t, DK, ND);
    gemm_bf16<1><<<g2(MROWS, ND), blk, 0, stream>>>(g1b, gw2t, P1, MROWS, ND, DK);

    // 4. beta + q.k precompute
    beta_k<<<MROWS, blk, 0, stream>>>(hs, b_w, bt);
    qk_dot<<<BHN * NT / 16, blk, 0, stream>>>(qn, kn, qk);

    // 5. scan -> out fp32 [B,T,H*Dv] (overwrites hsb region; full coverage)
    kda_scan<<<BHN * 8, blk, 0, stream>>>(qn, kn, vv, dc, bt, qk, out);

    // 6. gated RMSNorm -> ogb bf16 (aliases vv)
    gate_k<<<MROWS, blk, 0, stream>>>(out, P1, g_b2, onw, ogb);

    // 7. final projection (f32 out into d_out)
    wtrans<<<gt(ND, ND), blk, 0, stream>>>(o_w, WT, ND, ND);
    gemm_bf16<0><<<g2(MROWS, ND), blk, 0, stream>>>(ogb, WT, out, MROWS, ND, ND);
}

// Round 6
// 1442.185 us; speedup vs baseline: 3.6453x; 1.1562x over previous
//
#include <hip/hip_runtime.h>
#include <math.h>

// ---------------------------------------------------------------------------
// KimiDeltaAttention forward, MI355X. Round 6: chunked (UT-transform) delta
// rule, with the phase-2 MFMA switched from raw inline asm (round-5 failure:
// D/A-B register aliasing + missing MFMA wait-state s_nops) to the
// __builtin_amdgcn_mfma_f32_16x16x16bf16_1k intrinsic (hazards handled by
// compiler). Everything else identical to the passing round-4 stack.
// Shapes fixed: B=2, T=4096, D=2048, H=16, Dk=Dv=128.
// ---------------------------------------------------------------------------

constexpr int NB = 2, NT = 4096, ND = 2048, NH = 16, DK = 128, DV = 128;
constexpr int MROWS = NB * NT;   // 8192
constexpr int BHN   = NB * NH;   // 32
constexpr int CCH   = 16;        // chunk length
constexpr int NCH   = NT / CCH;  // 256 chunks per sequence

#define DEV static __device__ __forceinline__

typedef __attribute__((ext_vector_type(8))) short short8;   // bf16x8 MFMA frag
typedef __attribute__((ext_vector_type(4))) short short4v;  // bf16x4 MFMA frag
typedef __attribute__((ext_vector_type(4))) float f32x4;    // MFMA acc frag

DEV float sigmoidf_(float x) { return 1.0f / (1.0f + expf(-x)); }

DEV float bf2f(unsigned u) { return __uint_as_float(u << 16); }
DEV unsigned f2bf(float f) {  // round-to-nearest-even
    unsigned u = __float_as_uint(f);
    return (u + 0x7fffu + ((u >> 16) & 1u)) >> 16;
}
DEV unsigned pack2(float a, float b) { return f2bf(a) | (f2bf(b) << 16); }

// async global->LDS, 16B per lane (dst = wave-uniform base + lane*16)
DEV void gl2lds16(const unsigned short* g, unsigned short* l) {
    __builtin_amdgcn_global_load_lds(
        (const __attribute__((address_space(1))) unsigned int*)g,
        (__attribute__((address_space(3))) unsigned int*)l, 16, 0, 0);
}

// 16-lane butterfly sum via DPP
template <int CTRL>
DEV float dppadd(float x) {
    int y = __builtin_amdgcn_mov_dpp(__float_as_int(x), CTRL, 0xF, 0xF, true);
    return x + __int_as_float(y);
}
DEV float reduce16f(float x) {
    x = dppadd<0xB1>(x);
    x = dppadd<0x4E>(x);
    x = dppadd<0x141>(x);
    x = dppadd<0x140>(x);
    return x;
}

DEV float4 bflo(uint4 U) {
    return make_float4(bf2f(U.x & 0xffff), bf2f(U.x >> 16),
                       bf2f(U.y & 0xffff), bf2f(U.y >> 16));
}
DEV float4 bfhi(uint4 U) {
    return make_float4(bf2f(U.z & 0xffff), bf2f(U.z >> 16),
                       bf2f(U.w & 0xffff), bf2f(U.w >> 16));
}

// D = A(16x16) @ B(16x16)^T + C via v_mfma_f32_16x16x16_bf16.
// A/B frag: row = lane&15, k = (lane>>4)*4 + j. C/D: col = lane&15,
// row = (lane>>4)*4 + reg.
DEV f32x4 mfma16(short4v a, short4v b, f32x4 c) {
#if __has_builtin(__builtin_amdgcn_mfma_f32_16x16x16bf16_1k)
    return __builtin_amdgcn_mfma_f32_16x16x16bf16_1k(a, b, c, 0, 0, 0);
#elif __has_builtin(__builtin_amdgcn_mfma_f32_16x16x16_bf16)
    return __builtin_amdgcn_mfma_f32_16x16x16_bf16(a, b, c, 0, 0, 0);
#else
    // fallback: tied accumulator (D==C, no A/B aliasing possible) + s_nop
    // fencing for VALU->MFMA and MFMA->VALU wait states.
    asm volatile("s_nop 1\n\t"
                 "v_mfma_f32_16x16x16_bf16 %0, %1, %2, %0\n\t"
                 "s_nop 7\n\t"
                 "s_nop 7"
                 : "+v"(c) : "v"(a), "v"(b));
    return c;
#endif
}

// ---------------------------------------------------------------------------
// bf16 MFMA GEMM (unchanged from round 4): C[M,N] = A[M,K] @ Bt[N,K]^T.
// ---------------------------------------------------------------------------
template <int OUTBF>
__global__ __launch_bounds__(256) void gemm_bf16(
    const unsigned short* __restrict__ A, const unsigned short* __restrict__ Bt,
    void* __restrict__ Cv, int Md, int Nd, int Kd)
{
    __shared__ unsigned short As[128 * 64];
    __shared__ unsigned short Bs[128 * 64];

    const int nbx = Nd >> 7;
    const int bx = blockIdx.x % nbx;
    const int by = blockIdx.x / nbx;
    const int m0 = by << 7, n0 = bx << 7;
    const int tid = threadIdx.x;
    const int lane = tid & 63, wid = tid >> 6;
    const int wr = wid >> 1, wc = wid & 1;

    const int srow  = tid >> 3;
    const int sslot = (tid & 7) ^ (srow & 7);
    const unsigned short* ag = A  + (size_t)(m0 + srow) * Kd + sslot * 8;
    const unsigned short* bg = Bt + (size_t)(n0 + srow) * Kd + sslot * 8;
    const size_t rstep32 = (size_t)32 * Kd;
    unsigned short* aw = As + wid * 512;
    unsigned short* bw = Bs + wid * 512;

    const int rrow  = lane & 15;
    const int khalf = lane >> 4;
    const int rswz  = rrow & 7;

    f32x4 zf = {0.f, 0.f, 0.f, 0.f};
    f32x4 acc[4][4];
#pragma unroll
    for (int m = 0; m < 4; m++)
#pragma unroll
        for (int n = 0; n < 4; n++) acc[m][n] = zf;

    for (int k0 = 0; k0 < Kd; k0 += 64) {
#pragma unroll
        for (int i = 0; i < 4; i++) {
            gl2lds16(ag + (size_t)i * rstep32 + k0, aw + i * 2048);
            gl2lds16(bg + (size_t)i * rstep32 + k0, bw + i * 2048);
        }
        __syncthreads();
#pragma unroll
        for (int kk = 0; kk < 2; kk++) {
            const int slot = (kk * 4 + khalf) ^ rswz;
            short8 a[4], b[4];
#pragma unroll
            for (int m = 0; m < 4; m++)
                a[m] = *(const short8*)&As[(wr * 64 + m * 16 + rrow) * 64 + slot * 8];
#pragma unroll
            for (int n = 0; n < 4; n++)
                b[n] = *(const short8*)&Bs[(wc * 64 + n * 16 + rrow) * 64 + slot * 8];
#pragma unroll
            for (int m = 0; m < 4; m++)
#pragma unroll
                for (int n = 0; n < 4; n++)
                    acc[m][n] = __builtin_amdgcn_mfma_f32_16x16x32_bf16(
                        a[m], b[n], acc[m][n], 0, 0, 0);
        }
        __syncthreads();
    }

#pragma unroll
    for (int m = 0; m < 4; m++) {
        const int rowb = m0 + wr * 64 + m * 16 + khalf * 4;
#pragma unroll
        for (int n = 0; n < 4; n++) {
            const int col = n0 + wc * 64 + n * 16 + rrow;
#pragma unroll
            for (int r = 0; r < 4; r++) {
                const float v = acc[m][n][r];
                if (OUTBF)
                    ((unsigned short*)Cv)[(size_t)(rowb + r) * Nd + col] =
                        (unsigned short)f2bf(v);
                else
                    ((float*)Cv)[(size_t)(rowb + r) * Nd + col] = v;
            }
        }
    }
}

// ---------------------------------------------------------------------------
// Weight transpose + bf16 convert (unchanged).
// ---------------------------------------------------------------------------
__global__ __launch_bounds__(256) void wtrans(
    const float* __restrict__ W, unsigned short* __restrict__ Wt, int Kd, int Nd)
{
    __shared__ float T[64][65];
    const int nbk = Kd >> 6;
    const int bk = blockIdx.x % nbk, bn = blockIdx.x / nbk;
    const int k0 = bk << 6, n0 = bn << 6;
    const int tid = threadIdx.x;
    {
        const int r = tid >> 2, cg = tid & 3;
#pragma unroll
        for (int i = 0; i < 4; i++) {
            float4 f = *(const float4*)&W[(size_t)(k0 + r) * Nd + n0 + cg * 16 + i * 4];
            T[r][cg * 16 + i * 4 + 0] = f.x;
            T[r][cg * 16 + i * 4 + 1] = f.y;
            T[r][cg * 16 + i * 4 + 2] = f.z;
            T[r][cg * 16 + i * 4 + 3] = f.w;
        }
    }
    __syncthreads();
    {
        const int n = tid >> 2, kg = tid & 3;
#pragma unroll
        for (int i = 0; i < 2; i++) {
            unsigned o[4];
#pragma unroll
            for (int j = 0; j < 4; j++) {
                const int kk = kg * 16 + i * 8 + 2 * j;
                o[j] = pack2(T[kk][n], T[kk + 1][n]);
            }
            *(uint4*)&Wt[(size_t)(n0 + n) * Kd + k0 + kg * 16 + i * 8] =
                make_uint4(o[0], o[1], o[2], o[3]);
        }
    }
}

// f32 -> bf16 bulk convert (unchanged)
__global__ __launch_bounds__(256) void f2bf_k(
    const float* __restrict__ x, unsigned short* __restrict__ y, int n8)
{
    const int i = blockIdx.x * blockDim.x + threadIdx.x;
    if (i < n8) {
        float4 a = *(const float4*)&x[(size_t)i * 8];
        float4 b = *(const float4*)&x[(size_t)i * 8 + 4];
        uint4 o = make_uint4(pack2(a.x, a.y), pack2(a.z, a.w),
                             pack2(b.x, b.y), pack2(b.z, b.w));
        *(uint4*)&y[(size_t)i * 8] = o;
    }
}

// ---------------------------------------------------------------------------
// Causal depthwise conv (K=4) + silu (+l2norm) (unchanged from round 4).
// ---------------------------------------------------------------------------
template <int MODE>
__global__ __launch_bounds__(256) void conv_silu(
    const unsigned short* __restrict__ pre, const float* __restrict__ cw,
    unsigned short* __restrict__ outp)
{
    const int m = blockIdx.x;
    const int t = m & (NT - 1);
    const int b = m >> 12;
    const int tid = threadIdx.x;
    const int hd = tid * 8;
    const int h  = hd >> 7;
    const int d0 = hd & 127;

    float xr[4][8];
#pragma unroll
    for (int i = 0; i < 4; i++) {
        const int tt = t - 3 + i;
        if (tt >= 0) {
            uint4 u = *(const uint4*)(pre + (size_t)(m - 3 + i) * ND + hd);
            float4 lo = bflo(u), hi = bfhi(u);
            xr[i][0] = lo.x; xr[i][1] = lo.y; xr[i][2] = lo.z; xr[i][3] = lo.w;
            xr[i][4] = hi.x; xr[i][5] = hi.y; xr[i][6] = hi.z; xr[i][7] = hi.w;
        } else {
#pragma unroll
            for (int j = 0; j < 8; j++) xr[i][j] = 0.f;
        }
    }
    float y[8];
    float ssum = 0.f;
#pragma unroll
    for (int j = 0; j < 8; j++) {
        float4 w = *(const float4*)&cw[(size_t)(hd + j) * 4];
        float v = xr[0][j] * w.x + xr[1][j] * w.y + xr[2][j] * w.z + xr[3][j] * w.w;
        v = v * sigmoidf_(v);
        y[j] = v;
        ssum += v * v;
    }
    float scale = 1.f;
    if (MODE >= 1) {
        ssum = reduce16f(ssum);
        scale = rsqrtf(ssum + 1e-6f);
        if (MODE == 2) scale *= 0.08838834764831845f;
    }
    uint4 pk;
    pk.x = pack2(y[0] * scale, y[1] * scale);
    pk.y = pack2(y[2] * scale, y[3] * scale);
    pk.z = pack2(y[4] * scale, y[5] * scale);
    pk.w = pack2(y[6] * scale, y[7] * scale);
    unsigned short* dst = outp + ((size_t)(b * NH + h) * NT + t) * 128 + d0;
    *(uint4*)dst = pk;
}

// ---------------------------------------------------------------------------
// gk[b,h,t,d] = -exp(A_log[h]) * softplus(g + dt_bias) stored FP16, transposed
// ---------------------------------------------------------------------------
__global__ __launch_bounds__(256) void gk_k(
    const unsigned short* __restrict__ g, const float* __restrict__ A_log,
    const float* __restrict__ dtb, _Float16* __restrict__ gko)
{
    const int m = blockIdx.x;
    const int t = m & (NT - 1);
    const int b = m >> 12;
    const int tid = threadIdx.x;
    const int hd = tid * 8, h = hd >> 7, d0 = hd & 127;
    const float ea = expf(A_log[h]);
    uint4 u = *(const uint4*)(g + (size_t)m * ND + hd);
    float4 lo = bflo(u), hi = bfhi(u);
    float4 b0 = *(const float4*)&dtb[hd], b1 = *(const float4*)&dtb[hd + 4];
    float xin[8] = {lo.x + b0.x, lo.y + b0.y, lo.z + b0.z, lo.w + b0.w,
                    hi.x + b1.x, hi.y + b1.y, hi.z + b1.z, hi.w + b1.w};
    union { _Float16 h8[8]; uint4 u4; } up;
#pragma unroll
    for (int j = 0; j < 8; j++) {
        float x = xin[j];
        float sp = (x > 20.f) ? x : log1pf(expf(x));
        up.h8[j] = (_Float16)(-ea * sp);
    }
    _Float16* dst = gko + ((size_t)(b * NH + h) * NT + t) * 128 + d0;
    *(uint4*)dst = up.u4;
}

// ---------------------------------------------------------------------------
// beta[b,h,t] = sigmoid(hs @ b_w) (unchanged)
// ---------------------------------------------------------------------------
__global__ __launch_bounds__(256) void beta_k(
    const float* __restrict__ hs, const float* __restrict__ bw,
    float* __restrict__ bt)
{
    __shared__ float sh[ND];
    __shared__ float part[16][17];
    const int m = blockIdx.x, tid = threadIdx.x;
    ((float4*)sh)[tid * 2]     = ((const float4*)(hs + (size_t)m * ND))[tid * 2];
    ((float4*)sh)[tid * 2 + 1] = ((const float4*)(hs + (size_t)m * ND))[tid * 2 + 1];
    __syncthreads();
    const int h = tid & 15, seg = tid >> 4;
    float p = 0.f;
#pragma unroll 8
    for (int j = 0; j < 128; j++)
        p += sh[seg * 128 + j] * bw[(size_t)(seg * 128 + j) * 16 + h];
    part[seg][h] = p;
    __syncthreads();
    if (tid < 16) {
        float s = 0.f;
#pragma unroll
        for (int i = 0; i < 16; i++) s += part[i][tid];
        const int t = m & (NT - 1), b = m >> 12;
        bt[(size_t)(b * NH + tid) * NT + t] = sigmoidf_(s);
    }
}

// ---------------------------------------------------------------------------
// Phase 1 (parallel over 8192 chunks): per chunk of 16 steps compute
//   c = cumsum(gk); scores A_ij, B_ij (i>=j) with bounded exp(c_i-c_j);
//   solve (I + tril(A)diag(b)) [P|V'] = [kappa|v];  outputs written IN PLACE:
//   qn <- q~ = q*exp(c); kn <- P' = -P; vv <- V'; gkh <- khat^T [128,16];
//   BdB <- B_ij*b_j (f32); eCB <- exp(c_15) (f32).
// ---------------------------------------------------------------------------
__global__ __launch_bounds__(256) void kda_prep(
    unsigned short* __restrict__ qn, unsigned short* __restrict__ kn,
    unsigned short* __restrict__ vv, unsigned short* __restrict__ gkh,
    const float* __restrict__ bt,
    float* __restrict__ BdB, float* __restrict__ eCB)
{
    __shared__ float cL[16][132];
    __shared__ float kL[16][132];
    __shared__ float qL[16][132];
    __shared__ float kapL[16][132];
    __shared__ float AbL[16][16];
    __shared__ float bL[16];
    __shared__ float sx[16][264];

    const int blk = blockIdx.x;
    const int bh  = blk >> 8;
    const int cc  = blk & 255;
    const int tid = threadIdx.x;
    const size_t ebase  = ((size_t)bh * NT + cc * 16) * 128;
    const size_t chbase = (size_t)bh * NCH + cc;

    if (tid < 16) bL[tid] = bt[(size_t)bh * NT + cc * 16 + tid];

    if (tid < 128) {
        const int d = tid;
        float c = 0.f;
#pragma unroll
        for (int i = 0; i < 16; i++) {
            float g = (float)(((const _Float16*)gkh)[ebase + i * 128 + d]);
            c += g;
            cL[i][d] = c;
            float kv = bf2f(kn[ebase + i * 128 + d]);
            float qv = bf2f(qn[ebase + i * 128 + d]);
            kL[i][d] = kv; qL[i][d] = qv;
            kapL[i][d] = kv * expf(c);
        }
        eCB[chbase * 128 + d] = expf(c);   // c = cL[15][d]
    }
    __syncthreads();

    // khat^T write (all gk reads complete): row d = b_i*k_i[d]*exp(c15-c_i)
    if (tid < 128) {
        const int d = tid;
        const float clast = cL[15][d];
        unsigned u[8];
#pragma unroll
        for (int e = 0; e < 8; e++) {
            float v0 = bL[2 * e]     * kL[2 * e][d]     * expf(clast - cL[2 * e][d]);
            float v1 = bL[2 * e + 1] * kL[2 * e + 1][d] * expf(clast - cL[2 * e + 1][d]);
            u[e] = pack2(v0, v1);
        }
        uint4* dst = (uint4*)(gkh + chbase * 2048 + (size_t)d * 16);
        dst[0] = make_uint4(u[0], u[1], u[2], u[3]);
        dst[1] = make_uint4(u[4], u[5], u[6], u[7]);
    }

    // scores: thread (i,j), active for i>=j; full d-range
    const int si = tid >> 4, sj = tid & 15;
    float aAcc = 0.f, bAcc = 0.f;
    if (si >= sj) {
        for (int d4 = 0; d4 < 128; d4 += 4) {
            float4 ci = *(const float4*)&cL[si][d4];
            float4 cj = *(const float4*)&cL[sj][d4];
            float4 ki = *(const float4*)&kL[si][d4];
            float4 kj = *(const float4*)&kL[sj][d4];
            float4 qi = *(const float4*)&qL[si][d4];
            float w;
            w = expf(ci.x - cj.x); aAcc += ki.x * kj.x * w; bAcc += qi.x * kj.x * w;
            w = expf(ci.y - cj.y); aAcc += ki.y * kj.y * w; bAcc += qi.y * kj.y * w;
            w = expf(ci.z - cj.z); aAcc += ki.z * kj.z * w; bAcc += qi.z * kj.z * w;
            w = expf(ci.w - cj.w); aAcc += ki.w * kj.w * w; bAcc += qi.w * kj.w * w;
        }
    }
    if (si > sj) AbL[si][sj] = aAcc * bL[sj];
    BdB[chbase * 256 + si * 16 + sj] = bAcc * bL[sj];  // 0 for i<j (bAcc=0)
    __syncthreads();

    // solve M x = r, M = I + tril(Ab): columns 0..127 kappa, 128..255 v
    {
        const int col = tid;
        float x[16];
#pragma unroll
        for (int i = 0; i < 16; i++)
            x[i] = (col < 128) ? kapL[i][col]
                               : bf2f(vv[ebase + (size_t)i * 128 + (col - 128)]);
#pragma unroll
        for (int i = 1; i < 16; i++) {
            float s = x[i];
#pragma unroll
            for (int l = 0; l < 15; l++)
                if (l < i) s -= AbL[i][l] * x[l];
            x[i] = s;
        }
#pragma unroll
        for (int i = 0; i < 16; i++) sx[i][col] = x[i];
    }
    __syncthreads();

    // writes: P' = -x(kappa cols) -> kn; V' = x(v cols) -> vv; q~ -> qn
    {
        const int row = tid >> 4, d0 = (tid & 15) * 8;
        unsigned pu[4], vu[4], qu[4];
#pragma unroll
        for (int e = 0; e < 4; e++) {
            pu[e] = pack2(-sx[row][d0 + 2 * e], -sx[row][d0 + 2 * e + 1]);
            vu[e] = pack2(sx[row][128 + d0 + 2 * e], sx[row][128 + d0 + 2 * e + 1]);
            qu[e] = pack2(qL[row][d0 + 2 * e]     * expf(cL[row][d0 + 2 * e]),
                          qL[row][d0 + 2 * e + 1] * expf(cL[row][d0 + 2 * e + 1]));
        }
        const size_t ro = ebase + (size_t)row * 128 + d0;
        *(uint4*)(kn + ro) = make_uint4(pu[0], pu[1], pu[2], pu[3]);
        *(uint4*)(vv + ro) = make_uint4(vu[0], vu[1], vu[2], vu[3]);
        *(uint4*)(qn + ro) = make_uint4(qu[0], qu[1], qu[2], qu[3]);
    }
}

// ---------------------------------------------------------------------------
// Phase 2 (serial over 256 chunks, MFMA): grid 256 = vg(8) x bh(32), 1 wave.
// Per chunk: err = V' + P'@S ; o = q~@S + Bd@err ; S = eC*S + khat^T@err.
// S kept as f32 master + hi/lo bf16 fragment pairs in registers.
// ---------------------------------------------------------------------------
__global__ __launch_bounds__(64) void kda_scan2(
    const unsigned short* __restrict__ qn, const unsigned short* __restrict__ kn,
    const unsigned short* __restrict__ vv, const unsigned short* __restrict__ khat,
    const float* __restrict__ BdB, const float* __restrict__ eCB,
    float* __restrict__ osc)
{
    const int bh = blockIdx.x & 31;
    const int vg = blockIdx.x >> 5;
    const int lane = threadIdx.x;
    const int r16 = lane & 15, h4 = lane >> 4;
    const int bb = bh >> 4, hh = bh & 15;

    f32x4 Sm[8];
    short4v Shi[8], Slo[8];
    const short4v z4 = {0, 0, 0, 0};
#pragma unroll
    for (int t = 0; t < 8; t++) {
        Sm[t] = (f32x4){0.f, 0.f, 0.f, 0.f};
        Shi[t] = z4; Slo[t] = z4;
    }

    for (int cc = 0; cc < NCH; cc++) {
        const size_t ebase = ((size_t)bh * NT + cc * 16) * 128;
        const size_t chb = (size_t)bh * NCH + cc;
        short4v P[8], Q[8], KH[8];
        float4 eCt[8];
#pragma unroll
        for (int t = 0; t < 8; t++) {
            P[t]  = *(const short4v*)(kn + ebase + (size_t)r16 * 128 + t * 16 + h4 * 4);
            Q[t]  = *(const short4v*)(qn + ebase + (size_t)r16 * 128 + t * 16 + h4 * 4);
            KH[t] = *(const short4v*)(khat + chb * 2048 + (size_t)(t * 16 + r16) * 16 + h4 * 4);
            eCt[t] = *(const float4*)(eCB + chb * 128 + t * 16 + h4 * 4);
        }
        float4 bd4 = *(const float4*)(BdB + chb * 256 + (size_t)r16 * 16 + h4 * 4);
        short4v bdf;
        bdf[0] = (short)f2bf(bd4.x); bdf[1] = (short)f2bf(bd4.y);
        bdf[2] = (short)f2bf(bd4.z); bdf[3] = (short)f2bf(bd4.w);

        f32x4 accE, accO = {0.f, 0.f, 0.f, 0.f};
#pragma unroll
        for (int r = 0; r < 4; r++)
            accE[r] = bf2f(vv[ebase + (size_t)(h4 * 4 + r) * 128 + vg * 16 + r16]);

#pragma unroll
        for (int t = 0; t < 8; t++) {
            accE = mfma16(P[t], Shi[t], accE);
            accE = mfma16(P[t], Slo[t], accE);
            accO = mfma16(Q[t], Shi[t], accO);
            accO = mfma16(Q[t], Slo[t], accO);
        }
        // err -> bf16 B-frag (row v = lane&15, k = j = h4*4+reg)
        short4v ef;
        ef[0] = (short)f2bf(accE[0]); ef[1] = (short)f2bf(accE[1]);
        ef[2] = (short)f2bf(accE[2]); ef[3] = (short)f2bf(accE[3]);
        accO = mfma16(bdf, ef, accO);

        // state update per k'-tile
#pragma unroll
        for (int t = 0; t < 8; t++) {
            f32x4 ns;
            ns[0] = eCt[t].x * Sm[t][0];
            ns[1] = eCt[t].y * Sm[t][1];
            ns[2] = eCt[t].z * Sm[t][2];
            ns[3] = eCt[t].w * Sm[t][3];
            ns = mfma16(KH[t], ef, ns);
            Sm[t] = ns;
            short4v nh, nl;
#pragma unroll
            for (int r = 0; r < 4; r++) {
                unsigned hb = f2bf(ns[r]);
                nh[r] = (short)hb;
                nl[r] = (short)f2bf(ns[r] - bf2f(hb));
            }
            Shi[t] = nh; Slo[t] = nl;
        }

        // o write: rows i = h4*4+r, col hh*128 + vg*16 + r16
        const size_t obase = ((size_t)bb * NT + cc * 16) * ND + hh * 128 + vg * 16 + r16;
#pragma unroll
        for (int r = 0; r < 4; r++)
            osc[obase + (size_t)(h4 * 4 + r) * ND] = accO[r];
    }
}

// ---------------------------------------------------------------------------
// Gated RMSNorm epilogue (unchanged).
// ---------------------------------------------------------------------------
__global__ __launch_bounds__(256) void gate_k(
    const float* __restrict__ osc, const unsigned short* __restrict__ gateb,
    const float* __restrict__ gb2, const float* __restrict__ onw,
    unsigned short* __restrict__ ogb)
{
    const int m = blockIdx.x, tid = threadIdx.x;
    const int hd = tid * 8, d0 = hd & 127;
    const float* op = osc + (size_t)m * ND + hd;
    float4 o0 = *(const float4*)op, o1 = *(const float4*)(op + 4);
    float ssum = o0.x * o0.x + o0.y * o0.y + o0.z * o0.z + o0.w * o0.w +
                 o1.x * o1.x + o1.y * o1.y + o1.z * o1.z + o1.w * o1.w;
    ssum = reduce16f(ssum);
    const float r = rsqrtf(ssum * (1.0f / 128.0f) + 1e-5f);
    uint4 gu = *(const uint4*)(gateb + (size_t)m * ND + hd);
    float4 gl = bflo(gu), gh = bfhi(gu);
    float4 b0 = *(const float4*)&gb2[hd], b1 = *(const float4*)&gb2[hd + 4];
    float4 w0 = *(const float4*)&onw[d0], w1 = *(const float4*)&onw[d0 + 4];
    float res[8];
    res[0] = o0.x * r * w0.x * sigmoidf_(gl.x + b0.x);
    res[1] = o0.y * r * w0.y * sigmoidf_(gl.y + b0.y);
    res[2] = o0.z * r * w0.z * sigmoidf_(gl.z + b0.z);
    res[3] = o0.w * r * w0.w * sigmoidf_(gl.w + b0.w);
    res[4] = o1.x * r * w1.x * sigmoidf_(gh.x + b1.x);
    res[5] = o1.y * r * w1.y * sigmoidf_(gh.y + b1.y);
    res[6] = o1.z * r * w1.z * sigmoidf_(gh.z + b1.z);
    res[7] = o1.w * r * w1.w * sigmoidf_(gh.w + b1.w);
    uint4 pk;
    pk.x = pack2(res[0], res[1]); pk.y = pack2(res[2], res[3]);
    pk.z = pack2(res[4], res[5]); pk.w = pack2(res[6], res[7]);
    *(uint4*)(ogb + (size_t)m * ND + hd) = pk;
}

__global__ void diag_fill(float* out, float val, int n) {
    for (int i = blockIdx.x * blockDim.x + threadIdx.x; i < n; i += gridDim.x * blockDim.x)
        out[i] = val;
}

// ---------------------------------------------------------------------------
extern "C" void kernel_launch(void* const* d_in, const int* in_sizes, int n_in,
                              void* d_out, int out_size, void* d_ws, size_t ws_size,
                              hipStream_t stream)
{
    const float* hs    = (const float*)d_in[0];
    const float* q_w   = (const float*)d_in[1];
    const float* k_w   = (const float*)d_in[2];
    const float* v_w   = (const float*)d_in[3];
    const float* qcw   = (const float*)d_in[4];
    const float* kcw   = (const float*)d_in[5];
    const float* vcw   = (const float*)d_in[6];
    const float* f_w1  = (const float*)d_in[7];
    const float* f_w2  = (const float*)d_in[8];
    const float* b_w   = (const float*)d_in[9];
    const float* A_log = (const float*)d_in[10];
    const float* dt_b  = (const float*)d_in[11];
    const float* g_w1  = (const float*)d_in[12];
    const float* g_w2  = (const float*)d_in[13];
    const float* g_b2  = (const float*)d_in[14];
    const float* onw   = (const float*)d_in[15];
    const float* o_w   = (const float*)d_in[16];
    float* out = (float*)d_out;

    // ---- workspace layout (bytes), peak ~187 MB ----------------------------
    const size_t SEQ = (size_t)BHN * NT;           // 131072
    const size_t BF  = SEQ * 128 * 2;              // bf16 stream: 32 MiB
    char* wsb = (char*)d_ws;
    size_t off = 0;
    unsigned short* qn   = (unsigned short*)(wsb + off); off += BF;
    unsigned short* kn   = (unsigned short*)(wsb + off); off += BF;
    unsigned short* vv   = (unsigned short*)(wsb + off); off += BF;  // ogb post-scan
    unsigned short* dc   = (unsigned short*)(wsb + off); off += BF;  // gk fp16 -> khat
    unsigned short* P1   = (unsigned short*)(wsb + off); off += (size_t)MROWS * ND * 2;
    unsigned short* WT   = (unsigned short*)(wsb + off); off += (size_t)ND * ND * 2;
    unsigned short* fw1t = (unsigned short*)(wsb + off); off += (size_t)DK * ND * 2;
    unsigned short* fw2t = (unsigned short*)(wsb + off); off += (size_t)ND * DK * 2;
    unsigned short* gw1t = (unsigned short*)(wsb + off); off += (size_t)DK * ND * 2;
    unsigned short* gw2t = (unsigned short*)(wsb + off); off += (size_t)ND * DK * 2;
    unsigned short* f1b  = (unsigned short*)(wsb + off); off += (size_t)MROWS * DK * 2;
    unsigned short* g1b  = (unsigned short*)(wsb + off); off += (size_t)MROWS * DK * 2;
    float* bt  = (float*)(wsb + off); off += SEQ * 4;
    float* BdB = (float*)(wsb + off); off += (size_t)BHN * NCH * 256 * 4;  // 8 MiB
    float* eCB = (float*)(wsb + off); off += (size_t)BHN * NCH * 128 * 4;  // 4 MiB
    unsigned short* ogb = vv;
    unsigned short* hsb = (unsigned short*)d_out;

    if (ws_size < off) {
        diag_fill<<<512, 256, 0, stream>>>(out, 1.0e6f + (float)(ws_size >> 20), out_size);
        return;
    }

    dim3 blk(256);
    auto g2 = [](int Md, int Nd) { return dim3((unsigned)((Md >> 7) * (Nd >> 7))); };
    auto gt = [](int Kd, int Nd) { return dim3((unsigned)((Kd >> 6) * (Nd >> 6))); };

    // 0. hs -> bf16 (staged in d_out; consumed before scan2 overwrites)
    f2bf_k<<<(MROWS * ND / 8 + 255) / 256, blk, 0, stream>>>(hs, hsb, MROWS * ND / 8);

    // 1. q/k/v projections + conv/silu(/l2norm)
    wtrans<<<gt(ND, ND), blk, 0, stream>>>(q_w, WT, ND, ND);
    gemm_bf16<1><<<g2(MROWS, ND), blk, 0, stream>>>(hsb, WT, P1, MROWS, ND, ND);
    conv_silu<2><<<MROWS, blk, 0, stream>>>(P1, qcw, qn);
    wtrans<<<gt(ND, ND), blk, 0, stream>>>(k_w, WT, ND, ND);
    gemm_bf16<1><<<g2(MROWS, ND), blk, 0, stream>>>(hsb, WT, P1, MROWS, ND, ND);
    conv_silu<1><<<MROWS, blk, 0, stream>>>(P1, kcw, kn);
    wtrans<<<gt(ND, ND), blk, 0, stream>>>(v_w, WT, ND, ND);
    gemm_bf16<1><<<g2(MROWS, ND), blk, 0, stream>>>(hsb, WT, P1, MROWS, ND, ND);
    conv_silu<0><<<MROWS, blk, 0, stream>>>(P1, vcw, vv);

    // 2. decay path -> gk fp16
    wtrans<<<gt(ND, DK), blk, 0, stream>>>(f_w1, fw1t, ND, DK);
    gemm_bf16<1><<<g2(MROWS, DK), blk, 0, stream>>>(hsb, fw1t, f1b, MROWS, DK, ND);
    wtrans<<<gt(DK, ND), blk, 0, stream>>>(f_w2, fw2t, DK, ND);
    gemm_bf16<1><<<g2(MROWS, ND), blk, 0, stream>>>(f1b, fw2t, P1, MROWS, ND, DK);
    gk_k<<<MROWS, blk, 0, stream>>>(P1, A_log, dt_b, (_Float16*)dc);

    // 3. output gate preact -> P1 (survives scan, consumed by gate_k)
    wtrans<<<gt(ND, DK), blk, 0, stream>>>(g_w1, gw1t, ND, DK);
    gemm_bf16<1><<<g2(MROWS, DK), blk, 0, stream>>>(hsb, gw1t, g1b, MROWS, DK, ND);
    wtrans<<<gt(DK, ND), blk, 0, stream>>>(g_w2, gw2t, DK, ND);
    gemm_bf16<1><<<g2(MROWS, ND), blk, 0, stream>>>(g1b, gw2t, P1, MROWS, ND, DK);

    // 4. beta
    beta_k<<<MROWS, blk, 0, stream>>>(hs, b_w, bt);

    // 5. chunked delta rule: prep (parallel) + scan2 (serial chunks)
    kda_prep<<<BHN * NCH, blk, 0, stream>>>(qn, kn, vv, dc, bt, BdB, eCB);
    kda_scan2<<<256, 64, 0, stream>>>(qn, kn, vv, dc, BdB, eCB, out);

    // 6. gated RMSNorm -> ogb bf16 (aliases vv)
    gate_k<<<MROWS, blk, 0, stream>>>(out, P1, g_b2, onw, ogb);

    // 7. final projection
    wtrans<<<gt(ND, ND), blk, 0, stream>>>(o_w, WT, ND, ND);
    gemm_bf16<0><<<g2(MROWS, ND), blk, 0, stream>>>(ogb, WT, out, MROWS, ND, ND);
}

// Round 7
// 1305.695 us; speedup vs baseline: 4.0264x; 1.1045x over previous
//
#include <hip/hip_runtime.h>
#include <math.h>

// ---------------------------------------------------------------------------
// KimiDeltaAttention forward, MI355X. Round 7: kda_scan2 latency fix —
// register double-buffered chunk prefetch (A/B named sets, no runtime idx)
// + split accumulator chains (4 independent 8-MFMA chains). All other
// kernels identical to passing round 6.
// Shapes fixed: B=2, T=4096, D=2048, H=16, Dk=Dv=128.
// ---------------------------------------------------------------------------

constexpr int NB = 2, NT = 4096, ND = 2048, NH = 16, DK = 128, DV = 128;
constexpr int MROWS = NB * NT;   // 8192
constexpr int BHN   = NB * NH;   // 32
constexpr int CCH   = 16;        // chunk length
constexpr int NCH   = NT / CCH;  // 256 chunks per sequence

#define DEV static __device__ __forceinline__

typedef __attribute__((ext_vector_type(8))) short short8;   // bf16x8 MFMA frag
typedef __attribute__((ext_vector_type(4))) short short4v;  // bf16x4 MFMA frag
typedef __attribute__((ext_vector_type(4))) float f32x4;    // MFMA acc frag

DEV float sigmoidf_(float x) { return 1.0f / (1.0f + expf(-x)); }

DEV float bf2f(unsigned u) { return __uint_as_float(u << 16); }
DEV unsigned f2bf(float f) {  // round-to-nearest-even
    unsigned u = __float_as_uint(f);
    return (u + 0x7fffu + ((u >> 16) & 1u)) >> 16;
}
DEV unsigned pack2(float a, float b) { return f2bf(a) | (f2bf(b) << 16); }

// async global->LDS, 16B per lane (dst = wave-uniform base + lane*16)
DEV void gl2lds16(const unsigned short* g, unsigned short* l) {
    __builtin_amdgcn_global_load_lds(
        (const __attribute__((address_space(1))) unsigned int*)g,
        (__attribute__((address_space(3))) unsigned int*)l, 16, 0, 0);
}

// 16-lane butterfly sum via DPP
template <int CTRL>
DEV float dppadd(float x) {
    int y = __builtin_amdgcn_mov_dpp(__float_as_int(x), CTRL, 0xF, 0xF, true);
    return x + __int_as_float(y);
}
DEV float reduce16f(float x) {
    x = dppadd<0xB1>(x);
    x = dppadd<0x4E>(x);
    x = dppadd<0x141>(x);
    x = dppadd<0x140>(x);
    return x;
}

DEV float4 bflo(uint4 U) {
    return make_float4(bf2f(U.x & 0xffff), bf2f(U.x >> 16),
                       bf2f(U.y & 0xffff), bf2f(U.y >> 16));
}
DEV float4 bfhi(uint4 U) {
    return make_float4(bf2f(U.z & 0xffff), bf2f(U.z >> 16),
                       bf2f(U.w & 0xffff), bf2f(U.w >> 16));
}

// D = A(16x16) @ B(16x16)^T + C via v_mfma_f32_16x16x16_bf16.
// A/B frag: row = lane&15, k = (lane>>4)*4 + j. C/D: col = lane&15,
// row = (lane>>4)*4 + reg.
DEV f32x4 mfma16(short4v a, short4v b, f32x4 c) {
#if __has_builtin(__builtin_amdgcn_mfma_f32_16x16x16bf16_1k)
    return __builtin_amdgcn_mfma_f32_16x16x16bf16_1k(a, b, c, 0, 0, 0);
#elif __has_builtin(__builtin_amdgcn_mfma_f32_16x16x16_bf16)
    return __builtin_amdgcn_mfma_f32_16x16x16_bf16(a, b, c, 0, 0, 0);
#else
    asm volatile("s_nop 1\n\t"
                 "v_mfma_f32_16x16x16_bf16 %0, %1, %2, %0\n\t"
                 "s_nop 7\n\t"
                 "s_nop 7"
                 : "+v"(c) : "v"(a), "v"(b));
    return c;
#endif
}

// ---------------------------------------------------------------------------
// bf16 MFMA GEMM (unchanged from round 4): C[M,N] = A[M,K] @ Bt[N,K]^T.
// ---------------------------------------------------------------------------
template <int OUTBF>
__global__ __launch_bounds__(256) void gemm_bf16(
    const unsigned short* __restrict__ A, const unsigned short* __restrict__ Bt,
    void* __restrict__ Cv, int Md, int Nd, int Kd)
{
    __shared__ unsigned short As[128 * 64];
    __shared__ unsigned short Bs[128 * 64];

    const int nbx = Nd >> 7;
    const int bx = blockIdx.x % nbx;
    const int by = blockIdx.x / nbx;
    const int m0 = by << 7, n0 = bx << 7;
    const int tid = threadIdx.x;
    const int lane = tid & 63, wid = tid >> 6;
    const int wr = wid >> 1, wc = wid & 1;

    const int srow  = tid >> 3;
    const int sslot = (tid & 7) ^ (srow & 7);
    const unsigned short* ag = A  + (size_t)(m0 + srow) * Kd + sslot * 8;
    const unsigned short* bg = Bt + (size_t)(n0 + srow) * Kd + sslot * 8;
    const size_t rstep32 = (size_t)32 * Kd;
    unsigned short* aw = As + wid * 512;
    unsigned short* bw = Bs + wid * 512;

    const int rrow  = lane & 15;
    const int khalf = lane >> 4;
    const int rswz  = rrow & 7;

    f32x4 zf = {0.f, 0.f, 0.f, 0.f};
    f32x4 acc[4][4];
#pragma unroll
    for (int m = 0; m < 4; m++)
#pragma unroll
        for (int n = 0; n < 4; n++) acc[m][n] = zf;

    for (int k0 = 0; k0 < Kd; k0 += 64) {
#pragma unroll
        for (int i = 0; i < 4; i++) {
            gl2lds16(ag + (size_t)i * rstep32 + k0, aw + i * 2048);
            gl2lds16(bg + (size_t)i * rstep32 + k0, bw + i * 2048);
        }
        __syncthreads();
#pragma unroll
        for (int kk = 0; kk < 2; kk++) {
            const int slot = (kk * 4 + khalf) ^ rswz;
            short8 a[4], b[4];
#pragma unroll
            for (int m = 0; m < 4; m++)
                a[m] = *(const short8*)&As[(wr * 64 + m * 16 + rrow) * 64 + slot * 8];
#pragma unroll
            for (int n = 0; n < 4; n++)
                b[n] = *(const short8*)&Bs[(wc * 64 + n * 16 + rrow) * 64 + slot * 8];
#pragma unroll
            for (int m = 0; m < 4; m++)
#pragma unroll
                for (int n = 0; n < 4; n++)
                    acc[m][n] = __builtin_amdgcn_mfma_f32_16x16x32_bf16(
                        a[m], b[n], acc[m][n], 0, 0, 0);
        }
        __syncthreads();
    }

#pragma unroll
    for (int m = 0; m < 4; m++) {
        const int rowb = m0 + wr * 64 + m * 16 + khalf * 4;
#pragma unroll
        for (int n = 0; n < 4; n++) {
            const int col = n0 + wc * 64 + n * 16 + rrow;
#pragma unroll
            for (int r = 0; r < 4; r++) {
                const float v = acc[m][n][r];
                if (OUTBF)
                    ((unsigned short*)Cv)[(size_t)(rowb + r) * Nd + col] =
                        (unsigned short)f2bf(v);
                else
                    ((float*)Cv)[(size_t)(rowb + r) * Nd + col] = v;
            }
        }
    }
}

// ---------------------------------------------------------------------------
// Weight transpose + bf16 convert (unchanged).
// ---------------------------------------------------------------------------
__global__ __launch_bounds__(256) void wtrans(
    const float* __restrict__ W, unsigned short* __restrict__ Wt, int Kd, int Nd)
{
    __shared__ float T[64][65];
    const int nbk = Kd >> 6;
    const int bk = blockIdx.x % nbk, bn = blockIdx.x / nbk;
    const int k0 = bk << 6, n0 = bn << 6;
    const int tid = threadIdx.x;
    {
        const int r = tid >> 2, cg = tid & 3;
#pragma unroll
        for (int i = 0; i < 4; i++) {
            float4 f = *(const float4*)&W[(size_t)(k0 + r) * Nd + n0 + cg * 16 + i * 4];
            T[r][cg * 16 + i * 4 + 0] = f.x;
            T[r][cg * 16 + i * 4 + 1] = f.y;
            T[r][cg * 16 + i * 4 + 2] = f.z;
            T[r][cg * 16 + i * 4 + 3] = f.w;
        }
    }
    __syncthreads();
    {
        const int n = tid >> 2, kg = tid & 3;
#pragma unroll
        for (int i = 0; i < 2; i++) {
            unsigned o[4];
#pragma unroll
            for (int j = 0; j < 4; j++) {
                const int kk = kg * 16 + i * 8 + 2 * j;
                o[j] = pack2(T[kk][n], T[kk + 1][n]);
            }
            *(uint4*)&Wt[(size_t)(n0 + n) * Kd + k0 + kg * 16 + i * 8] =
                make_uint4(o[0], o[1], o[2], o[3]);
        }
    }
}

// f32 -> bf16 bulk convert (unchanged)
__global__ __launch_bounds__(256) void f2bf_k(
    const float* __restrict__ x, unsigned short* __restrict__ y, int n8)
{
    const int i = blockIdx.x * blockDim.x + threadIdx.x;
    if (i < n8) {
        float4 a = *(const float4*)&x[(size_t)i * 8];
        float4 b = *(const float4*)&x[(size_t)i * 8 + 4];
        uint4 o = make_uint4(pack2(a.x, a.y), pack2(a.z, a.w),
                             pack2(b.x, b.y), pack2(b.z, b.w));
        *(uint4*)&y[(size_t)i * 8] = o;
    }
}

// ---------------------------------------------------------------------------
// Causal depthwise conv (K=4) + silu (+l2norm) (unchanged).
// ---------------------------------------------------------------------------
template <int MODE>
__global__ __launch_bounds__(256) void conv_silu(
    const unsigned short* __restrict__ pre, const float* __restrict__ cw,
    unsigned short* __restrict__ outp)
{
    const int m = blockIdx.x;
    const int t = m & (NT - 1);
    const int b = m >> 12;
    const int tid = threadIdx.x;
    const int hd = tid * 8;
    const int h  = hd >> 7;
    const int d0 = hd & 127;

    float xr[4][8];
#pragma unroll
    for (int i = 0; i < 4; i++) {
        const int tt = t - 3 + i;
        if (tt >= 0) {
            uint4 u = *(const uint4*)(pre + (size_t)(m - 3 + i) * ND + hd);
            float4 lo = bflo(u), hi = bfhi(u);
            xr[i][0] = lo.x; xr[i][1] = lo.y; xr[i][2] = lo.z; xr[i][3] = lo.w;
            xr[i][4] = hi.x; xr[i][5] = hi.y; xr[i][6] = hi.z; xr[i][7] = hi.w;
        } else {
#pragma unroll
            for (int j = 0; j < 8; j++) xr[i][j] = 0.f;
        }
    }
    float y[8];
    float ssum = 0.f;
#pragma unroll
    for (int j = 0; j < 8; j++) {
        float4 w = *(const float4*)&cw[(size_t)(hd + j) * 4];
        float v = xr[0][j] * w.x + xr[1][j] * w.y + xr[2][j] * w.z + xr[3][j] * w.w;
        v = v * sigmoidf_(v);
        y[j] = v;
        ssum += v * v;
    }
    float scale = 1.f;
    if (MODE >= 1) {
        ssum = reduce16f(ssum);
        scale = rsqrtf(ssum + 1e-6f);
        if (MODE == 2) scale *= 0.08838834764831845f;
    }
    uint4 pk;
    pk.x = pack2(y[0] * scale, y[1] * scale);
    pk.y = pack2(y[2] * scale, y[3] * scale);
    pk.z = pack2(y[4] * scale, y[5] * scale);
    pk.w = pack2(y[6] * scale, y[7] * scale);
    unsigned short* dst = outp + ((size_t)(b * NH + h) * NT + t) * 128 + d0;
    *(uint4*)dst = pk;
}

// ---------------------------------------------------------------------------
// gk[b,h,t,d] = -exp(A_log[h]) * softplus(g + dt_bias) stored FP16 (unchanged)
// ---------------------------------------------------------------------------
__global__ __launch_bounds__(256) void gk_k(
    const unsigned short* __restrict__ g, const float* __restrict__ A_log,
    const float* __restrict__ dtb, _Float16* __restrict__ gko)
{
    const int m = blockIdx.x;
    const int t = m & (NT - 1);
    const int b = m >> 12;
    const int tid = threadIdx.x;
    const int hd = tid * 8, h = hd >> 7, d0 = hd & 127;
    const float ea = expf(A_log[h]);
    uint4 u = *(const uint4*)(g + (size_t)m * ND + hd);
    float4 lo = bflo(u), hi = bfhi(u);
    float4 b0 = *(const float4*)&dtb[hd], b1 = *(const float4*)&dtb[hd + 4];
    float xin[8] = {lo.x + b0.x, lo.y + b0.y, lo.z + b0.z, lo.w + b0.w,
                    hi.x + b1.x, hi.y + b1.y, hi.z + b1.z, hi.w + b1.w};
    union { _Float16 h8[8]; uint4 u4; } up;
#pragma unroll
    for (int j = 0; j < 8; j++) {
        float x = xin[j];
        float sp = (x > 20.f) ? x : log1pf(expf(x));
        up.h8[j] = (_Float16)(-ea * sp);
    }
    _Float16* dst = gko + ((size_t)(b * NH + h) * NT + t) * 128 + d0;
    *(uint4*)dst = up.u4;
}

// ---------------------------------------------------------------------------
// beta[b,h,t] = sigmoid(hs @ b_w) (unchanged)
// ---------------------------------------------------------------------------
__global__ __launch_bounds__(256) void beta_k(
    const float* __restrict__ hs, const float* __restrict__ bw,
    float* __restrict__ bt)
{
    __shared__ float sh[ND];
    __shared__ float part[16][17];
    const int m = blockIdx.x, tid = threadIdx.x;
    ((float4*)sh)[tid * 2]     = ((const float4*)(hs + (size_t)m * ND))[tid * 2];
    ((float4*)sh)[tid * 2 + 1] = ((const float4*)(hs + (size_t)m * ND))[tid * 2 + 1];
    __syncthreads();
    const int h = tid & 15, seg = tid >> 4;
    float p = 0.f;
#pragma unroll 8
    for (int j = 0; j < 128; j++)
        p += sh[seg * 128 + j] * bw[(size_t)(seg * 128 + j) * 16 + h];
    part[seg][h] = p;
    __syncthreads();
    if (tid < 16) {
        float s = 0.f;
#pragma unroll
        for (int i = 0; i < 16; i++) s += part[i][tid];
        const int t = m & (NT - 1), b = m >> 12;
        bt[(size_t)(b * NH + tid) * NT + t] = sigmoidf_(s);
    }
}

// ---------------------------------------------------------------------------
// Phase 1 kda_prep (unchanged from round 6).
// ---------------------------------------------------------------------------
__global__ __launch_bounds__(256) void kda_prep(
    unsigned short* __restrict__ qn, unsigned short* __restrict__ kn,
    unsigned short* __restrict__ vv, unsigned short* __restrict__ gkh,
    const float* __restrict__ bt,
    float* __restrict__ BdB, float* __restrict__ eCB)
{
    __shared__ float cL[16][132];
    __shared__ float kL[16][132];
    __shared__ float qL[16][132];
    __shared__ float kapL[16][132];
    __shared__ float AbL[16][16];
    __shared__ float bL[16];
    __shared__ float sx[16][264];

    const int blk = blockIdx.x;
    const int bh  = blk >> 8;
    const int cc  = blk & 255;
    const int tid = threadIdx.x;
    const size_t ebase  = ((size_t)bh * NT + cc * 16) * 128;
    const size_t chbase = (size_t)bh * NCH + cc;

    if (tid < 16) bL[tid] = bt[(size_t)bh * NT + cc * 16 + tid];

    if (tid < 128) {
        const int d = tid;
        float c = 0.f;
#pragma unroll
        for (int i = 0; i < 16; i++) {
            float g = (float)(((const _Float16*)gkh)[ebase + i * 128 + d]);
            c += g;
            cL[i][d] = c;
            float kv = bf2f(kn[ebase + i * 128 + d]);
            float qv = bf2f(qn[ebase + i * 128 + d]);
            kL[i][d] = kv; qL[i][d] = qv;
            kapL[i][d] = kv * expf(c);
        }
        eCB[chbase * 128 + d] = expf(c);
    }
    __syncthreads();

    if (tid < 128) {
        const int d = tid;
        const float clast = cL[15][d];
        unsigned u[8];
#pragma unroll
        for (int e = 0; e < 8; e++) {
            float v0 = bL[2 * e]     * kL[2 * e][d]     * expf(clast - cL[2 * e][d]);
            float v1 = bL[2 * e + 1] * kL[2 * e + 1][d] * expf(clast - cL[2 * e + 1][d]);
            u[e] = pack2(v0, v1);
        }
        uint4* dst = (uint4*)(gkh + chbase * 2048 + (size_t)d * 16);
        dst[0] = make_uint4(u[0], u[1], u[2], u[3]);
        dst[1] = make_uint4(u[4], u[5], u[6], u[7]);
    }

    const int si = tid >> 4, sj = tid & 15;
    float aAcc = 0.f, bAcc = 0.f;
    if (si >= sj) {
        for (int d4 = 0; d4 < 128; d4 += 4) {
            float4 ci = *(const float4*)&cL[si][d4];
            float4 cj = *(const float4*)&cL[sj][d4];
            float4 ki = *(const float4*)&kL[si][d4];
            float4 kj = *(const float4*)&kL[sj][d4];
            float4 qi = *(const float4*)&qL[si][d4];
            float w;
            w = expf(ci.x - cj.x); aAcc += ki.x * kj.x * w; bAcc += qi.x * kj.x * w;
            w = expf(ci.y - cj.y); aAcc += ki.y * kj.y * w; bAcc += qi.y * kj.y * w;
            w = expf(ci.z - cj.z); aAcc += ki.z * kj.z * w; bAcc += qi.z * kj.z * w;
            w = expf(ci.w - cj.w); aAcc += ki.w * kj.w * w; bAcc += qi.w * kj.w * w;
        }
    }
    if (si > sj) AbL[si][sj] = aAcc * bL[sj];
    BdB[chbase * 256 + si * 16 + sj] = bAcc * bL[sj];
    __syncthreads();

    {
        const int col = tid;
        float x[16];
#pragma unroll
        for (int i = 0; i < 16; i++)
            x[i] = (col < 128) ? kapL[i][col]
                               : bf2f(vv[ebase + (size_t)i * 128 + (col - 128)]);
#pragma unroll
        for (int i = 1; i < 16; i++) {
            float s = x[i];
#pragma unroll
            for (int l = 0; l < 15; l++)
                if (l < i) s -= AbL[i][l] * x[l];
            x[i] = s;
        }
#pragma unroll
        for (int i = 0; i < 16; i++) sx[i][col] = x[i];
    }
    __syncthreads();

    {
        const int row = tid >> 4, d0 = (tid & 15) * 8;
        unsigned pu[4], vu[4], qu[4];
#pragma unroll
        for (int e = 0; e < 4; e++) {
            pu[e] = pack2(-sx[row][d0 + 2 * e], -sx[row][d0 + 2 * e + 1]);
            vu[e] = pack2(sx[row][128 + d0 + 2 * e], sx[row][128 + d0 + 2 * e + 1]);
            qu[e] = pack2(qL[row][d0 + 2 * e]     * expf(cL[row][d0 + 2 * e]),
                          qL[row][d0 + 2 * e + 1] * expf(cL[row][d0 + 2 * e + 1]));
        }
        const size_t ro = ebase + (size_t)row * 128 + d0;
        *(uint4*)(kn + ro) = make_uint4(pu[0], pu[1], pu[2], pu[3]);
        *(uint4*)(vv + ro) = make_uint4(vu[0], vu[1], vu[2], vu[3]);
        *(uint4*)(qn + ro) = make_uint4(qu[0], qu[1], qu[2], qu[3]);
    }
}

// ---------------------------------------------------------------------------
// Phase 2 (serial over 256 chunks, MFMA), round 7: register double-buffered
// prefetch (named A/B sets) + split accumulator chains.
// Per chunk: err = V' + P'@S ; o = q~@S + Bd@err ; S = eC*S + khat^T@err.
// ---------------------------------------------------------------------------
__global__ __launch_bounds__(64) void kda_scan2(
    const unsigned short* __restrict__ qn, const unsigned short* __restrict__ kn,
    const unsigned short* __restrict__ vv, const unsigned short* __restrict__ khat,
    const float* __restrict__ BdB, const float* __restrict__ eCB,
    float* __restrict__ osc)
{
    const int bh = blockIdx.x & 31;
    const int vg = blockIdx.x >> 5;
    const int lane = threadIdx.x;
    const int r16 = lane & 15, h4 = lane >> 4;
    const int bb = bh >> 4, hh = bh & 15;

    f32x4 Sm[8];
    short4v Shi[8], Slo[8];
    const short4v z4 = {0, 0, 0, 0};
#pragma unroll
    for (int t = 0; t < 8; t++) {
        Sm[t] = (f32x4){0.f, 0.f, 0.f, 0.f};
        Shi[t] = z4; Slo[t] = z4;
    }

    // per-chunk register set load (all indices compile-time after unroll)
    auto loadc = [&](int cc, short4v* P, short4v* Q, short4v* KH,
                     float4* eCt, short4v& bdf, f32x4& accInit) {
        const size_t ebase = ((size_t)bh * NT + cc * 16) * 128;
        const size_t chb = (size_t)bh * NCH + cc;
#pragma unroll
        for (int t = 0; t < 8; t++) {
            P[t]  = *(const short4v*)(kn + ebase + (size_t)r16 * 128 + t * 16 + h4 * 4);
            Q[t]  = *(const short4v*)(qn + ebase + (size_t)r16 * 128 + t * 16 + h4 * 4);
            KH[t] = *(const short4v*)(khat + chb * 2048 + (size_t)(t * 16 + r16) * 16 + h4 * 4);
            eCt[t] = *(const float4*)(eCB + chb * 128 + t * 16 + h4 * 4);
        }
        float4 bd4 = *(const float4*)(BdB + chb * 256 + (size_t)r16 * 16 + h4 * 4);
        bdf[0] = (short)f2bf(bd4.x); bdf[1] = (short)f2bf(bd4.y);
        bdf[2] = (short)f2bf(bd4.z); bdf[3] = (short)f2bf(bd4.w);
#pragma unroll
        for (int r = 0; r < 4; r++)
            accInit[r] = bf2f(vv[ebase + (size_t)(h4 * 4 + r) * 128 + vg * 16 + r16]);
    };

    // compute one chunk from a register set; updates Sm/Shi/Slo, writes o
    auto compute = [&](int cc, const short4v* P, const short4v* Q,
                       const short4v* KH, const float4* eCt,
                       short4v bdf, f32x4 accInit) {
        f32x4 e0 = accInit, e1 = {0.f, 0.f, 0.f, 0.f};
        f32x4 o0 = {0.f, 0.f, 0.f, 0.f}, o1 = {0.f, 0.f, 0.f, 0.f};
#pragma unroll
        for (int t = 0; t < 8; t += 2) {     // 4 independent MFMA chains
            e0 = mfma16(P[t],     Shi[t],     e0);
            e1 = mfma16(P[t + 1], Shi[t + 1], e1);
            o0 = mfma16(Q[t],     Shi[t],     o0);
            o1 = mfma16(Q[t + 1], Shi[t + 1], o1);
            e0 = mfma16(P[t],     Slo[t],     e0);
            e1 = mfma16(P[t + 1], Slo[t + 1], e1);
            o0 = mfma16(Q[t],     Slo[t],     o0);
            o1 = mfma16(Q[t + 1], Slo[t + 1], o1);
        }
        f32x4 accE;
        accE[0] = e0[0] + e1[0]; accE[1] = e0[1] + e1[1];
        accE[2] = e0[2] + e1[2]; accE[3] = e0[3] + e1[3];
        f32x4 accO;
        accO[0] = o0[0] + o1[0]; accO[1] = o0[1] + o1[1];
        accO[2] = o0[2] + o1[2]; accO[3] = o0[3] + o1[3];

        short4v ef;
        ef[0] = (short)f2bf(accE[0]); ef[1] = (short)f2bf(accE[1]);
        ef[2] = (short)f2bf(accE[2]); ef[3] = (short)f2bf(accE[3]);
        accO = mfma16(bdf, ef, accO);

#pragma unroll
        for (int t = 0; t < 8; t++) {
            f32x4 ns;
            ns[0] = eCt[t].x * Sm[t][0];
            ns[1] = eCt[t].y * Sm[t][1];
            ns[2] = eCt[t].z * Sm[t][2];
            ns[3] = eCt[t].w * Sm[t][3];
            ns = mfma16(KH[t], ef, ns);
            Sm[t] = ns;
            short4v nh, nl;
#pragma unroll
            for (int r = 0; r < 4; r++) {
                unsigned hb = f2bf(ns[r]);
                nh[r] = (short)hb;
                nl[r] = (short)f2bf(ns[r] - bf2f(hb));
            }
            Shi[t] = nh; Slo[t] = nl;
        }

        const size_t obase = ((size_t)bb * NT + cc * 16) * ND + hh * 128 + vg * 16 + r16;
#pragma unroll
        for (int r = 0; r < 4; r++)
            osc[obase + (size_t)(h4 * 4 + r) * ND] = accO[r];
    };

    // named double-buffer sets (rule #20: no runtime-indexed selection)
    short4v Pa[8], Qa[8], KHa[8], Pb[8], Qb[8], KHb[8];
    float4 eCa[8], eCb[8];
    short4v bda, bdb;
    f32x4 ia, ib;

    loadc(0, Pa, Qa, KHa, eCa, bda, ia);
    for (int cc = 0; cc < NCH; cc += 2) {
        loadc(cc + 1, Pb, Qb, KHb, eCb, bdb, ib);   // prefetch odd chunk
        compute(cc, Pa, Qa, KHa, eCa, bda, ia);     // compute even chunk
        if (cc + 2 < NCH)
            loadc(cc + 2, Pa, Qa, KHa, eCa, bda, ia);  // prefetch next even
        compute(cc + 1, Pb, Qb, KHb, eCb, bdb, ib); // compute odd chunk
    }
}

// ---------------------------------------------------------------------------
// Gated RMSNorm epilogue (unchanged).
// ---------------------------------------------------------------------------
__global__ __launch_bounds__(256) void gate_k(
    const float* __restrict__ osc, const unsigned short* __restrict__ gateb,
    const float* __restrict__ gb2, const float* __restrict__ onw,
    unsigned short* __restrict__ ogb)
{
    const int m = blockIdx.x, tid = threadIdx.x;
    const int hd = tid * 8, d0 = hd & 127;
    const float* op = osc + (size_t)m * ND + hd;
    float4 o0 = *(const float4*)op, o1 = *(const float4*)(op + 4);
    float ssum = o0.x * o0.x + o0.y * o0.y + o0.z * o0.z + o0.w * o0.w +
                 o1.x * o1.x + o1.y * o1.y + o1.z * o1.z + o1.w * o1.w;
    ssum = reduce16f(ssum);
    const float r = rsqrtf(ssum * (1.0f / 128.0f) + 1e-5f);
    uint4 gu = *(const uint4*)(gateb + (size_t)m * ND + hd);
    float4 gl = bflo(gu), gh = bfhi(gu);
    float4 b0 = *(const float4*)&gb2[hd], b1 = *(const float4*)&gb2[hd + 4];
    float4 w0 = *(const float4*)&onw[d0], w1 = *(const float4*)&onw[d0 + 4];
    float res[8];
    res[0] = o0.x * r * w0.x * sigmoidf_(gl.x + b0.x);
    res[1] = o0.y * r * w0.y * sigmoidf_(gl.y + b0.y);
    res[2] = o0.z * r * w0.z * sigmoidf_(gl.z + b0.z);
    res[3] = o0.w * r * w0.w * sigmoidf_(gl.w + b0.w);
    res[4] = o1.x * r * w1.x * sigmoidf_(gh.x + b1.x);
    res[5] = o1.y * r * w1.y * sigmoidf_(gh.y + b1.y);
    res[6] = o1.z * r * w1.z * sigmoidf_(gh.z + b1.z);
    res[7] = o1.w * r * w1.w * sigmoidf_(gh.w + b1.w);
    uint4 pk;
    pk.x = pack2(res[0], res[1]); pk.y = pack2(res[2], res[3]);
    pk.z = pack2(res[4], res[5]); pk.w = pack2(res[6], res[7]);
    *(uint4*)(ogb + (size_t)m * ND + hd) = pk;
}

__global__ void diag_fill(float* out, float val, int n) {
    for (int i = blockIdx.x * blockDim.x + threadIdx.x; i < n; i += gridDim.x * blockDim.x)
        out[i] = val;
}

// ---------------------------------------------------------------------------
extern "C" void kernel_launch(void* const* d_in, const int* in_sizes, int n_in,
                              void* d_out, int out_size, void* d_ws, size_t ws_size,
                              hipStream_t stream)
{
    const float* hs    = (const float*)d_in[0];
    const float* q_w   = (const float*)d_in[1];
    const float* k_w   = (const float*)d_in[2];
    const float* v_w   = (const float*)d_in[3];
    const float* qcw   = (const float*)d_in[4];
    const float* kcw   = (const float*)d_in[5];
    const float* vcw   = (const float*)d_in[6];
    const float* f_w1  = (const float*)d_in[7];
    const float* f_w2  = (const float*)d_in[8];
    const float* b_w   = (const float*)d_in[9];
    const float* A_log = (const float*)d_in[10];
    const float* dt_b  = (const float*)d_in[11];
    const float* g_w1  = (const float*)d_in[12];
    const float* g_w2  = (const float*)d_in[13];
    const float* g_b2  = (const float*)d_in[14];
    const float* onw   = (const float*)d_in[15];
    const float* o_w   = (const float*)d_in[16];
    float* out = (float*)d_out;

    // ---- workspace layout (bytes), peak ~187 MB ----------------------------
    const size_t SEQ = (size_t)BHN * NT;           // 131072
    const size_t BF  = SEQ * 128 * 2;              // bf16 stream: 32 MiB
    char* wsb = (char*)d_ws;
    size_t off = 0;
    unsigned short* qn   = (unsigned short*)(wsb + off); off += BF;
    unsigned short* kn   = (unsigned short*)(wsb + off); off += BF;
    unsigned short* vv   = (unsigned short*)(wsb + off); off += BF;  // ogb post-scan
    unsigned short* dc   = (unsigned short*)(wsb + off); off += BF;  // gk fp16 -> khat
    unsigned short* P1   = (unsigned short*)(wsb + off); off += (size_t)MROWS * ND * 2;
    unsigned short* WT   = (unsigned short*)(wsb + off); off += (size_t)ND * ND * 2;
    unsigned short* fw1t = (unsigned short*)(wsb + off); off += (size_t)DK * ND * 2;
    unsigned short* fw2t = (unsigned short*)(wsb + off); off += (size_t)ND * DK * 2;
    unsigned short* gw1t = (unsigned short*)(wsb + off); off += (size_t)DK * ND * 2;
    unsigned short* gw2t = (unsigned short*)(wsb + off); off += (size_t)ND * DK * 2;
    unsigned short* f1b  = (unsigned short*)(wsb + off); off += (size_t)MROWS * DK * 2;
    unsigned short* g1b  = (unsigned short*)(wsb + off); off += (size_t)MROWS * DK * 2;
    float* bt  = (float*)(wsb + off); off += SEQ * 4;
    float* BdB = (float*)(wsb + off); off += (size_t)BHN * NCH * 256 * 4;  // 8 MiB
    float* eCB = (float*)(wsb + off); off += (size_t)BHN * NCH * 128 * 4;  // 4 MiB
    unsigned short* ogb = vv;
    unsigned short* hsb = (unsigned short*)d_out;

    if (ws_size < off) {
        diag_fill<<<512, 256, 0, stream>>>(out, 1.0e6f + (float)(ws_size >> 20), out_size);
        return;
    }

    dim3 blk(256);
    auto g2 = [](int Md, int Nd) { return dim3((unsigned)((Md >> 7) * (Nd >> 7))); };
    auto gt = [](int Kd, int Nd) { return dim3((unsigned)((Kd >> 6) * (Nd >> 6))); };

    // 0. hs -> bf16 (staged in d_out; consumed before scan2 overwrites)
    f2bf_k<<<(MROWS * ND / 8 + 255) / 256, blk, 0, stream>>>(hs, hsb, MROWS * ND / 8);

    // 1. q/k/v projections + conv/silu(/l2norm)
    wtrans<<<gt(ND, ND), blk, 0, stream>>>(q_w, WT, ND, ND);
    gemm_bf16<1><<<g2(MROWS, ND), blk, 0, stream>>>(hsb, WT, P1, MROWS, ND, ND);
    conv_silu<2><<<MROWS, blk, 0, stream>>>(P1, qcw, qn);
    wtrans<<<gt(ND, ND), blk, 0, stream>>>(k_w, WT, ND, ND);
    gemm_bf16<1><<<g2(MROWS, ND), blk, 0, stream>>>(hsb, WT, P1, MROWS, ND, ND);
    conv_silu<1><<<MROWS, blk, 0, stream>>>(P1, kcw, kn);
    wtrans<<<gt(ND, ND), blk, 0, stream>>>(v_w, WT, ND, ND);
    gemm_bf16<1><<<g2(MROWS, ND), blk, 0, stream>>>(hsb, WT, P1, MROWS, ND, ND);
    conv_silu<0><<<MROWS, blk, 0, stream>>>(P1, vcw, vv);

    // 2. decay path -> gk fp16
    wtrans<<<gt(ND, DK), blk, 0, stream>>>(f_w1, fw1t, ND, DK);
    gemm_bf16<1><<<g2(MROWS, DK), blk, 0, stream>>>(hsb, fw1t, f1b, MROWS, DK, ND);
    wtrans<<<gt(DK, ND), blk, 0, stream>>>(f_w2, fw2t, DK, ND);
    gemm_bf16<1><<<g2(MROWS, ND), blk, 0, stream>>>(f1b, fw2t, P1, MROWS, ND, DK);
    gk_k<<<MROWS, blk, 0, stream>>>(P1, A_log, dt_b, (_Float16*)dc);

    // 3. output gate preact -> P1 (survives scan, consumed by gate_k)
    wtrans<<<gt(ND, DK), blk, 0, stream>>>(g_w1, gw1t, ND, DK);
    gemm_bf16<1><<<g2(MROWS, DK), blk, 0, stream>>>(hsb, gw1t, g1b, MROWS, DK, ND);
    wtrans<<<gt(DK, ND), blk, 0, stream>>>(g_w2, gw2t, DK, ND);
    gemm_bf16<1><<<g2(MROWS, ND), blk, 0, stream>>>(g1b, gw2t, P1, MROWS, ND, DK);

    // 4. beta
    beta_k<<<MROWS, blk, 0, stream>>>(hs, b_w, bt);

    // 5. chunked delta rule: prep (parallel) + scan2 (serial chunks)
    kda_prep<<<BHN * NCH, blk, 0, stream>>>(qn, kn, vv, dc, bt, BdB, eCB);
    kda_scan2<<<256, 64, 0, stream>>>(qn, kn, vv, dc, BdB, eCB, out);

    // 6. gated RMSNorm -> ogb bf16 (aliases vv)
    gate_k<<<MROWS, blk, 0, stream>>>(out, P1, g_b2, onw, ogb);

    // 7. final projection
    wtrans<<<gt(ND, ND), blk, 0, stream>>>(o_w, WT, ND, ND);
    gemm_bf16<0><<<g2(MROWS, ND), blk, 0, stream>>>(ogb, WT, out, MROWS, ND, ND);
}